// Round 7
// baseline (775.361 us; speedup 1.0000x reference)
//
#include <hip/hip_runtime.h>
#include <math.h>

#define NN 32768
#define NE 524288

typedef __attribute__((ext_vector_type(8))) short short8v;
typedef __attribute__((ext_vector_type(4))) float f32x4;

__device__ __forceinline__ float siluf(float x){
  return x * __builtin_amdgcn_rcpf(1.0f + __expf(-x));
}

__device__ __forceinline__ unsigned short f2bf(float x){
  unsigned int b = __float_as_uint(x);
  unsigned int r = ((b >> 16) & 1u) + 0x7fffu;
  return (unsigned short)((b + r) >> 16);
}

__device__ __forceinline__ unsigned int pk2(float a, float b){
  return (unsigned int)f2bf(a) | ((unsigned int)f2bf(b) << 16);
}

__device__ __forceinline__ float bf2f(unsigned short v){
  return __uint_as_float(((unsigned int)v) << 16);
}

__device__ const int d_PL1[11] = {0,1,2,0,1,1,2,0,1,2,2};
__device__ const int d_PL2[11] = {0,1,2,1,0,2,1,2,1,0,2};
__device__ const int d_PL3[11] = {0,0,0,1,1,1,1,2,2,2,2};

// ---------------------------------------------------------------------------
// CG init (1/PATH_NORM folded). All paths have even l1+l2+l3 -> real part.
// ---------------------------------------------------------------------------
__device__ double factd(int n){ double r=1.0; for(int i=2;i<=n;++i) r*=(double)i; return r; }

__device__ double su2_elem(int l1,int l2,int l3,int m1,int m2){
  int m3=m1+m2;
  if (m3 < -l3 || m3 > l3) return 0.0;
  double pref = sqrt((double)(2*l3+1)*factd(l3+l1-l2)*factd(l3-l1+l2)*factd(l1+l2-l3)/factd(l1+l2+l3+1));
  pref *= sqrt(factd(l3+m3)*factd(l3-m3)*factd(l1-m1)*factd(l1+m1)*factd(l2-m2)*factd(l2+m2));
  double s=0.0;
  for (int k=0;k<=l1+l2-l3;++k){
    int t1=l1+l2-l3-k, t2=l1-m1-k, t3=l2+m2-k, t4=l3-l2+m1+k, t5=l3-l1-m2+k;
    if (t1<0||t2<0||t3<0||t4<0||t5<0) continue;
    double d = factd(k)*factd(t1)*factd(t2)*factd(t3)*factd(t4)*factd(t5);
    s += ((k&1)? -1.0:1.0)/d;
  }
  return pref*s;
}

__device__ void q_elem(int l,int a,int i,double& re,double& im){
  re=0.0; im=0.0;
  const double is2 = 0.7071067811865476;
  int m = a - l;
  if (m==0){ if (i==l) re=1.0; return; }
  if (m>0){
    if (i==l+m)      re = (m&1)? -is2: is2;
    else if (i==l-m) re = is2;
  } else {
    int mm=-m;
    if (i==l-mm)      im = is2;
    else if (i==l+mm) im = (mm&1)? is2 : -is2;
  }
}

__global__ void cg_kernel(float* __restrict__ cgout){
  int p = blockIdx.x;
  int t = threadIdx.x;
  if (t >= 125) return;
  int a = t/25, b = (t/5)%5, c = t%5;
  int l1=d_PL1[p], l2=d_PL2[p], l3=d_PL3[p];
  int n1=2*l1+1, n2=2*l2+1, n3=2*l3+1;
  float outv = 0.0f;
  if (a<n1 && b<n2 && c<n3){
    double acc = 0.0;
    for (int i=0;i<n1;++i)
      for (int j=0;j<n2;++j){
        int m1=i-l1, m2=j-l2;
        int m3=m1+m2;
        if (m3 < -l3 || m3 > l3) continue;
        double cv = su2_elem(l1,l2,l3,m1,m2);
        if (cv==0.0) continue;
        int k = m3 + l3;
        double a1r,a1i,a2r,a2i,a3r,a3i;
        q_elem(l1,a,i,a1r,a1i);
        q_elem(l2,b,j,a2r,a2i);
        q_elem(l3,c,k,a3r,a3i);
        double re = (a1r*a2r - a1i*a2i)*a3r + (a1r*a2i + a1i*a2r)*a3i;
        acc += cv*re;
      }
    double invn = (l3==0)? 0.5773502691896258 : 0.5;
    outv = (float)(acc*invn);
  }
  cgout[p*125 + (a*5+b)*5 + c] = outv;
}

// ---------------------------------------------------------------------------
// Node up-projection (scaled 0.25)
// ---------------------------------------------------------------------------
__global__ __launch_bounds__(256) void node_up_kernel(
    const float* __restrict__ nf,
    const float* __restrict__ W0,
    const float* __restrict__ W1,
    const float* __restrict__ W2,
    float* __restrict__ mtab)
{
  int gidx = blockIdx.x*256 + threadIdx.x;
  if (gidx >= NN*144) return;
  int n = gidx/144;
  int col = gidx - n*144;
  const float* f = nf + (size_t)n*144;
  float acc = 0.f;
  if (col < 16){
    int o = col;
    #pragma unroll
    for (int c=0;c<16;++c) acc += f[c]*W0[c*16+o];
  } else if (col < 64){
    int idx = col-16;
    int o = idx/3, i = idx - o*3;
    #pragma unroll
    for (int c=0;c<16;++c) acc += f[16+c*3+i]*W1[c*16+o];
  } else {
    int idx = col-64;
    int o = idx/5, i = idx - o*5;
    #pragma unroll
    for (int c=0;c<16;++c) acc += f[64+c*5+i]*W2[c*16+o];
  }
  mtab[gidx] = 0.25f*acc;
}

// ---------------------------------------------------------------------------
// CSR build
// ---------------------------------------------------------------------------
__global__ __launch_bounds__(256) void hist_kernel(
    const int* __restrict__ recv, int* __restrict__ counts)
{
  int e = blockIdx.x*256 + threadIdx.x;
  if (e < NE) atomicAdd(&counts[recv[e]], 1);
}

__global__ __launch_bounds__(1024) void scan_kernel(
    const int* __restrict__ counts, int* __restrict__ offsets)
{
  __shared__ int part[1024];
  int t = threadIdx.x;
  int local[32];
  int s = 0;
  #pragma unroll
  for (int i=0;i<32;++i){ local[i]=counts[t*32+i]; s+=local[i]; }
  part[t]=s;
  __syncthreads();
  for (int off=1; off<1024; off<<=1){
    int v = (t>=off)? part[t-off] : 0;
    __syncthreads();
    part[t] += v;
    __syncthreads();
  }
  int run = part[t] - s;
  #pragma unroll
  for (int i=0;i<32;++i){ offsets[t*32+i]=run; run+=local[i]; }
  if (t==1023) offsets[NN]=run;
}

__global__ __launch_bounds__(256) void scatter_kernel(
    const int* __restrict__ recv, const int* __restrict__ offsets,
    int* __restrict__ cursor, int* __restrict__ edge_sorted)
{
  int e = blockIdx.x*256 + threadIdx.x;
  if (e < NE){
    int r = recv[e];
    int pos = atomicAdd(&cursor[r], 1);
    edge_sorted[offsets[r] + pos] = e;
  }
}

__global__ __launch_bounds__(256) void find_bounds_kernel(
    const int* __restrict__ offsets, int* __restrict__ nb, int NC)
{
  int n = blockIdx.x*256 + threadIdx.x;
  if (n == 0){ nb[0] = 0; nb[NC] = NN; }
  if (n >= NN) return;
  int o0 = offsets[n], o1 = offsets[n+1];
  for (int i=1; i<NC; ++i){
    long long Ti = (long long)NE*i/NC;
    if (o0 <= Ti && Ti < o1) nb[i] = n+1;
  }
}

// ---------------------------------------------------------------------------
// Pack Wm1/Wm2 into bf16 B-fragment order.
// ---------------------------------------------------------------------------
__global__ __launch_bounds__(256) void pack_w_kernel(
    const float* __restrict__ Wm1, const float* __restrict__ Wm2,
    unsigned short* __restrict__ Wm1p, unsigned short* __restrict__ Wm2p)
{
  int t = blockIdx.x*256 + threadIdx.x;
  if (t < 4096){
    int j = t & 7, lane = (t>>3)&63, ks = (t>>9)&1, ni = t>>10;
    int k = ks*32 + (lane>>4)*8 + j;
    int col = ni*16 + (lane&15);
    Wm1p[t] = f2bf(Wm1[k*64+col]);
  }
  int t2 = t - 4096;
  if (t2 >= 0 && t2 < 11264){
    int j = t2 & 7, lane = (t2>>3)&63, ks = (t2>>9)&1, ni = t2>>10;
    int k = ks*32 + (lane>>4)*8 + j;
    int col = ni*16 + (lane&15);
    Wm2p[t2] = f2bf(Wm2[k*176+col]);
  }
}

// ---------------------------------------------------------------------------
// Fused edge kernel: radial MLP (MFMA) + mix (MFMA, stays in LDS) + tensor
// product, writing msgb[slot][144] bf16. One wave = 64 edges.
// ---------------------------------------------------------------------------
template<int PIDX,int L1,int L2,int L3>
__device__ __forceinline__ void do_path4f(
    const float* __restrict__ cgtab,
    const unsigned short* __restrict__ mixT,  // [16 slots][11 paths][16 ch] bf16
    int s_loc, int c0,
    const float (&y1)[3], const float (&y2)[5],
    const float (&x0)[4], const float (&x1)[4][3], const float (&x2)[4][5],
    float (&msg0)[4], float (&msg1)[4][3], float (&msg2)[4][5])
{
  constexpr int d1=2*L1+1, d2=2*L2+1, d3=2*L3+1;
  const float* cgp = cgtab + PIDX*125;

  float yv[d2];
  if constexpr (L2==0){ yv[0]=1.0f; }
  else if constexpr (L2==1){ yv[0]=y1[0]; yv[1]=y1[1]; yv[2]=y1[2]; }
  else {
    #pragma unroll
    for (int j=0;j<5;++j) yv[j]=y2[j];
  }

  float M[d1][d3];
  #pragma unroll
  for (int iu=0;iu<d1;++iu){
    #pragma unroll
    for (int k=0;k<d3;++k){
      float acc = 0.f;
      #pragma unroll
      for (int j=0;j<d2;++j) acc += yv[j]*cgp[(iu*5+j)*5+k];
      M[iu][k]=acc;
    }
  }

  uint2 um = *(const uint2*)(mixT + ((s_loc*11 + PIDX)*16 + c0));
  float mx[4];
  mx[0] = __uint_as_float(um.x << 16);
  mx[1] = __uint_as_float(um.x & 0xffff0000u);
  mx[2] = __uint_as_float(um.y << 16);
  mx[3] = __uint_as_float(um.y & 0xffff0000u);

  #pragma unroll
  for (int c=0;c<4;++c){
    #pragma unroll
    for (int k=0;k<d3;++k){
      float t = 0.f;
      #pragma unroll
      for (int iu=0;iu<d1;++iu){
        float xv = (L1==0)? x0[c] : (L1==1? x1[c][iu] : x2[c][iu]);
        t += xv*M[iu][k];
      }
      if constexpr (L3==0)      msg0[c]    += mx[c]*t;
      else if constexpr (L3==1) msg1[c][k] += mx[c]*t;
      else                      msg2[c][k] += mx[c]*t;
    }
  }
}

__global__ __launch_bounds__(256) void edge_fused_kernel(
    const float* __restrict__ vectors,
    const int* __restrict__ senders,
    const int* __restrict__ edge_sorted,
    const int* __restrict__ offsets,
    const int* __restrict__ nb,
    const float* __restrict__ Wm0,
    const unsigned short* __restrict__ Wm1p,
    const unsigned short* __restrict__ Wm2p,
    const float* __restrict__ mtab,
    const float* __restrict__ cgtab,
    int ci,
    unsigned short* __restrict__ msgb)
{
  __shared__ unsigned short lds_h[4][4096];   // 8 KB/wave; reused as mixT (2816 shorts)
  __shared__ float lds_u[4][64][4];           // ux,uy,uz,scale
  __shared__ int   lds_es[4][64];             // sender id per slot

  int sbase = offsets[nb[ci]];
  int nE = offsets[nb[ci+1]] - sbase;
  int tid = threadIdx.x;
  int wid = tid >> 6;
  int lane = tid & 63;
  int g = lane >> 4;
  int l15 = lane & 15;
  int wb = blockIdx.x*256 + wid*64;
  int slot = wb + lane;

  // ---- phase A: per-lane radial basis + layer 1 ----
  float vx=0.f, vy=0.f, vz=0.f;
  int snd = 0;
  if (slot < nE){
    int e = edge_sorted[sbase + slot];
    vx = vectors[(size_t)e*3+0];
    vy = vectors[(size_t)e*3+1];
    vz = vectors[(size_t)e*3+2];
    snd = senders[e];
  }
  float r = sqrtf(vx*vx + vy*vy + vz*vz);
  float safe = (r > 1e-9f) ? r : 1.0f;
  float inv_safe = 1.0f/safe;

  const float PIf = 3.14159265358979f;
  float xc = fminf(r*0.25f, 1.0f);
  float s1 = __sinf(PIf*xc);
  float c1 = __cosf(PIf*xc);
  float env = 0.5f*(c1 + 1.0f);
  float pref = 0.70710678118f * env * inv_safe;
  float rb[8];
  {
    float sk=s1, ck=c1;
    rb[0]=pref*sk;
    #pragma unroll
    for (int k=1;k<8;++k){
      float sn = sk*c1 + ck*s1;
      float cn = ck*c1 - sk*s1;
      sk=sn; ck=cn;
      rb[k]=pref*sk;
    }
  }

  float h[64];
  #pragma unroll
  for (int o=0;o<64;++o) h[o]=0.f;
  #pragma unroll
  for (int i=0;i<8;++i){
    float ri = rb[i];
    #pragma unroll
    for (int o=0;o<64;++o) h[o] += ri*Wm0[i*64+o];
  }

  unsigned short* Lh = lds_h[wid];
  #pragma unroll
  for (int c=0;c<8;++c){
    union { unsigned int u[4]; short8v v; } pk;
    #pragma unroll
    for (int w=0;w<4;++w){
      float a0 = siluf(h[c*8+2*w  ]*0.3535533906f);
      float a1 = siluf(h[c*8+2*w+1]*0.3535533906f);
      pk.u[w] = pk2(a0, a1);
    }
    *(short8v*)(Lh + ((size_t)(c*64 + lane))*8) = pk.v;
  }
  lds_u[wid][lane][0] = vx*inv_safe;
  lds_u[wid][lane][1] = vy*inv_safe;
  lds_u[wid][lane][2] = vz*inv_safe;
  lds_u[wid][lane][3] = (r == 0.0f) ? 0.0f : 0.125f;
  lds_es[wid][lane] = snd;

  __syncthreads();

  // ---- h2 = silu((h @ Wm1)/8) via MFMA, back into Lh ----
  short8v a[8];
  #pragma unroll
  for (int mi=0;mi<4;++mi){
    #pragma unroll
    for (int ks=0;ks<2;++ks)
      a[mi*2+ks] = *(short8v*)(Lh + ((size_t)((ks*4+g)*64 + mi*16 + l15))*8);
  }
  #pragma unroll 1
  for (int ni=0;ni<4;++ni){
    short8v b0 = *(short8v*)(Wm1p + ((size_t)((ni*2+0)*64 + lane))*8);
    short8v b1 = *(short8v*)(Wm1p + ((size_t)((ni*2+1)*64 + lane))*8);
    int chnk = ni*2 + (l15>>3);
    int cb = l15 & 7;
    #pragma unroll
    for (int mi=0;mi<4;++mi){
      f32x4 acc = {0.f,0.f,0.f,0.f};
      acc = __builtin_amdgcn_mfma_f32_16x16x32_bf16(a[mi*2+0], b0, acc, 0,0,0);
      acc = __builtin_amdgcn_mfma_f32_16x16x32_bf16(a[mi*2+1], b1, acc, 0,0,0);
      #pragma unroll
      for (int reg=0;reg<4;++reg){
        int row = mi*16 + g*4 + reg;
        Lh[((size_t)(chnk*64 + row))*8 + cb] = f2bf(siluf(acc[reg]*0.125f));
      }
    }
  }

  // ---- load all A2 fragments, then Lh is reusable as mixT ----
  short8v a2[8];
  #pragma unroll
  for (int mi=0;mi<4;++mi){
    #pragma unroll
    for (int ks=0;ks<2;++ks)
      a2[mi*2+ks] = *(short8v*)(Lh + ((size_t)((ks*4+g)*64 + mi*16 + l15))*8);
  }
  __syncthreads();   // drain LDS reads before mixT overwrites Lh

  unsigned short* mixT = Lh;   // [16][11][16] bf16 = 2816 shorts
  const float SQ3  = 1.73205080757f;
  const float SQ15 = 3.87298334621f;

  // ---- per 16-slot group: mix via MFMA -> LDS -> tensor product ----
  #pragma unroll 1
  for (int mi=0;mi<4;++mi){
    // scale per row (rows = mi*16 + g*4 + reg)
    float scv[4];
    #pragma unroll
    for (int reg=0;reg<4;++reg)
      scv[reg] = lds_u[wid][mi*16 + g*4 + reg][3];

    #pragma unroll 1
    for (int ni=0;ni<11;++ni){
      short8v b0 = *(short8v*)(Wm2p + ((size_t)((ni*2+0)*64 + lane))*8);
      short8v b1 = *(short8v*)(Wm2p + ((size_t)((ni*2+1)*64 + lane))*8);
      f32x4 acc = {0.f,0.f,0.f,0.f};
      acc = __builtin_amdgcn_mfma_f32_16x16x32_bf16(a2[mi*2+0], b0, acc, 0,0,0);
      acc = __builtin_amdgcn_mfma_f32_16x16x32_bf16(a2[mi*2+1], b1, acc, 0,0,0);
      #pragma unroll
      for (int reg=0;reg<4;++reg){
        int s_loc = g*4 + reg;
        mixT[(s_loc*11 + ni)*16 + l15] = f2bf(acc[reg]*scv[reg]);
      }
    }

    // tensor product for slots mi*16 .. mi*16+15 (4 lanes per slot)
    int s_loc = lane >> 2;
    int slot_g = mi*16 + s_loc;          // wave-local row
    int myslot = wb + slot_g;            // chunk-local slot
    int q = lane & 3;
    int c0 = q*4;

    f32x4 uu = *(f32x4*)(&lds_u[wid][slot_g][0]);
    int snd2 = lds_es[wid][slot_g];
    float ux = uu[0], uy = uu[1], uz = uu[2];

    float y1[3] = { SQ3*uy, SQ3*uz, SQ3*ux };
    float y2[5] = { SQ15*ux*uy, SQ15*uy*uz, 1.11803398875f*(3.f*uz*uz-1.f),
                    SQ15*ux*uz, 1.93649167310f*(ux*ux-uy*uy) };

    const float* xp = mtab + (size_t)snd2*144;
    float x0[4];
    float x1[4][3];
    float x2[4][5];
    #pragma unroll
    for (int c=0;c<4;++c) x0[c] = xp[c0+c];
    #pragma unroll
    for (int c=0;c<4;++c){
      #pragma unroll
      for (int i=0;i<3;++i) x1[c][i] = xp[16 + (c0+c)*3 + i];
    }
    #pragma unroll
    for (int c=0;c<4;++c){
      #pragma unroll
      for (int i=0;i<5;++i) x2[c][i] = xp[64 + (c0+c)*5 + i];
    }

    float msg0[4];
    float msg1[4][3];
    float msg2[4][5];
    #pragma unroll
    for (int c=0;c<4;++c){
      msg0[c]=0.f;
      #pragma unroll
      for (int i=0;i<3;++i) msg1[c][i]=0.f;
      #pragma unroll
      for (int i=0;i<5;++i) msg2[c][i]=0.f;
    }

    do_path4f< 0,0,0,0>(cgtab,mixT,s_loc,c0,y1,y2,x0,x1,x2,msg0,msg1,msg2);
    do_path4f< 1,1,1,0>(cgtab,mixT,s_loc,c0,y1,y2,x0,x1,x2,msg0,msg1,msg2);
    do_path4f< 2,2,2,0>(cgtab,mixT,s_loc,c0,y1,y2,x0,x1,x2,msg0,msg1,msg2);
    do_path4f< 3,0,1,1>(cgtab,mixT,s_loc,c0,y1,y2,x0,x1,x2,msg0,msg1,msg2);
    do_path4f< 4,1,0,1>(cgtab,mixT,s_loc,c0,y1,y2,x0,x1,x2,msg0,msg1,msg2);
    do_path4f< 5,1,2,1>(cgtab,mixT,s_loc,c0,y1,y2,x0,x1,x2,msg0,msg1,msg2);
    do_path4f< 6,2,1,1>(cgtab,mixT,s_loc,c0,y1,y2,x0,x1,x2,msg0,msg1,msg2);
    do_path4f< 7,0,2,2>(cgtab,mixT,s_loc,c0,y1,y2,x0,x1,x2,msg0,msg1,msg2);
    do_path4f< 8,1,1,2>(cgtab,mixT,s_loc,c0,y1,y2,x0,x1,x2,msg0,msg1,msg2);
    do_path4f< 9,2,0,2>(cgtab,mixT,s_loc,c0,y1,y2,x0,x1,x2,msg0,msg1,msg2);
    do_path4f<10,2,2,2>(cgtab,mixT,s_loc,c0,y1,y2,x0,x1,x2,msg0,msg1,msg2);

    if (myslot < nE){
      unsigned short* mr = msgb + (size_t)myslot*144;
      {
        uint2 w;
        w.x = pk2(msg0[0], msg0[1]);
        w.y = pk2(msg0[2], msg0[3]);
        *(uint2*)(mr + c0) = w;
      }
      {
        unsigned short* p = mr + 16 + c0*3;
        uint2 w0, w1, w2;
        w0.x = pk2(msg1[0][0], msg1[0][1]);
        w0.y = pk2(msg1[0][2], msg1[1][0]);
        w1.x = pk2(msg1[1][1], msg1[1][2]);
        w1.y = pk2(msg1[2][0], msg1[2][1]);
        w2.x = pk2(msg1[2][2], msg1[3][0]);
        w2.y = pk2(msg1[3][1], msg1[3][2]);
        *(uint2*)(p) = w0;
        *(uint2*)(p+4) = w1;
        *(uint2*)(p+8) = w2;
      }
      {
        unsigned short* p = mr + 64 + c0*5;
        #pragma unroll
        for (int w=0; w<5; ++w){
          int i0 = w*4;
          float v0 = msg2[(i0+0)/5][(i0+0)%5];
          float v1 = msg2[(i0+1)/5][(i0+1)%5];
          float v2 = msg2[(i0+2)/5][(i0+2)%5];
          float v3 = msg2[(i0+3)/5][(i0+3)%5];
          uint2 ww;
          ww.x = pk2(v0, v1);
          ww.y = pk2(v2, v3);
          *(uint2*)(p + i0) = ww;
        }
      }
    }
  }
}

// ---------------------------------------------------------------------------
// Segmented sum over sorted msgb rows: thread per (node, col).
// ---------------------------------------------------------------------------
__global__ __launch_bounds__(256) void seg_sum_kernel(
    const int* __restrict__ offsets,
    const int* __restrict__ nb,
    const unsigned short* __restrict__ msgb,
    int ci,
    float* __restrict__ out)
{
  int t = blockIdx.x*256 + threadIdx.x;
  int n = t/144;
  int col = t - n*144;
  if (n >= NN) return;
  int nlo = nb[ci], nhi = nb[ci+1];
  if (n < nlo || n >= nhi) return;
  int cbase = offsets[nlo];
  int j0 = offsets[n] - cbase;
  int j1 = offsets[n+1] - cbase;
  float acc = 0.f;
  for (int j=j0; j<j1; ++j){
    acc += bf2f(msgb[(size_t)j*144 + col]);
  }
  out[(size_t)n*144 + col] = acc;
}

// ---------------------------------------------------------------------------
// Final node update, in-place on out.
// ---------------------------------------------------------------------------
__global__ __launch_bounds__(256) void node_out_kernel(
    const float* __restrict__ nf,
    const int* __restrict__ species,
    const float* __restrict__ Wd0,
    const float* __restrict__ Wd1,
    const float* __restrict__ Wd2,
    const float* __restrict__ Wsk0,
    const float* __restrict__ Wsk1,
    const float* __restrict__ Wsk2,
    const float* agg,
    float* out)
{
  int t = blockIdx.x*256 + threadIdx.x;
  int n = t >> 4;
  int o = t & 15;
  if (n >= NN) return;
  const float* an = agg + (size_t)n*144;
  const float* f  = nf  + (size_t)n*144;
  int sp = species[n];
  const float* wk0 = Wsk0 + sp*768;
  const float* wk1 = Wsk1 + sp*256;
  const float* wk2 = Wsk2 + sp*256;

  float sa0=0,sa1=0,sa2=0, sf0=0,sf1=0,sf2=0;
  #pragma unroll
  for (int c=0;c<16;++c){
    float aa = an[c], ff = f[c];
    sa0 += aa*Wd0[c*48+o];
    sa1 += aa*Wd0[c*48+16+o];
    sa2 += aa*Wd0[c*48+32+o];
    sf0 += ff*wk0[c*48+o];
    sf1 += ff*wk0[c*48+16+o];
    sf2 += ff*wk0[c*48+32+o];
  }
  float s0 = 0.0625f*sa0 + 0.25f*sf0;
  float s1 = 0.0625f*sa1 + 0.25f*sf1;
  float s2 = 0.0625f*sa2 + 0.25f*sf2;
  float scvv = siluf(s0);
  float g1  = siluf(s1);
  float g2  = siluf(s2);

  float v[3];
  #pragma unroll
  for (int i=0;i<3;++i){
    float av=0, fv=0;
    #pragma unroll
    for (int c=0;c<16;++c){
      av += an[16+c*3+i]*Wd1[c*16+o];
      fv += f[16+c*3+i]*wk1[c*16+o];
    }
    v[i] = (0.0625f*av + 0.25f*fv)*g1;
  }
  float q[5];
  #pragma unroll
  for (int i=0;i<5;++i){
    float av=0, fv=0;
    #pragma unroll
    for (int c=0;c<16;++c){
      av += an[64+c*5+i]*Wd2[c*16+o];
      fv += f[64+c*5+i]*wk2[c*16+o];
    }
    q[i] = (0.0625f*av + 0.25f*fv)*g2;
  }

  float* on = out + (size_t)n*144;
  on[o] = scvv;
  #pragma unroll
  for (int i=0;i<3;++i) on[16+o*3+i] = v[i];
  #pragma unroll
  for (int i=0;i<5;++i) on[64+o*5+i] = q[i];
}

// ---------------------------------------------------------------------------
extern "C" void kernel_launch(void* const* d_in, const int* in_sizes, int n_in,
                              void* d_out, int out_size, void* d_ws, size_t ws_size,
                              hipStream_t stream)
{
  const float* vectors    = (const float*)d_in[0];
  const float* node_feats = (const float*)d_in[1];
  const int*   species    = (const int*)d_in[2];
  const int*   senders    = (const int*)d_in[3];
  const int*   receivers  = (const int*)d_in[4];
  const float* W_up0 = (const float*)d_in[5];
  const float* W_up1 = (const float*)d_in[6];
  const float* W_up2 = (const float*)d_in[7];
  const float* Wm0   = (const float*)d_in[8];
  const float* Wm1   = (const float*)d_in[9];
  const float* Wm2   = (const float*)d_in[10];
  const float* Wd0   = (const float*)d_in[11];
  const float* Wd1   = (const float*)d_in[12];
  const float* Wd2   = (const float*)d_in[13];
  const float* Wsk0  = (const float*)d_in[14];
  const float* Wsk1  = (const float*)d_in[15];
  const float* Wsk2  = (const float*)d_in[16];
  float* out = (float*)d_out;
  float* ws  = (float*)d_ws;

  // ws layout (float units):
  // [cg 2048][mtab NN*144][counts NN][cursor NN][offsets NN+64][edge_sorted NE]
  // [nb 16][Wm1p 2048][Wm2p 5632][msgb bf16 rows]
  float* cgbuf = ws;
  float* mtab  = ws + 2048;
  int* counts      = (int*)(ws + 2048 + (size_t)NN*144);
  int* cursor      = counts + NN;
  int* offsets     = cursor + NN;
  int* edge_sorted = offsets + NN + 64;
  int* nb          = edge_sorted + NE;
  unsigned short* Wm1p = (unsigned short*)(nb + 16);
  unsigned short* Wm2p = Wm1p + 4096;
  unsigned short* msgb = Wm2p + 11264;

  size_t fixed_f = 2048 + (size_t)NN*144 + NN + NN + (NN+64) + NE + 16 + 2048 + 5632;
  size_t ws_f = ws_size/4;
  // per-edge ws need: msgb 144 bf16 = 72 floats
  long long cap_rows = (ws_f > fixed_f) ? (long long)((ws_f - fixed_f)/72) : 0;
  long long capm = cap_rows - 4096;
  if (capm < 16384) capm = 16384;
  int NC = (int)((NE + capm - 1)/capm);
  if (NC < 1) NC = 1;
  if (NC > 15) NC = 15;

  hipMemsetAsync(counts, 0, 2*(size_t)NN*sizeof(int), stream);
  cg_kernel<<<11, 128, 0, stream>>>(cgbuf);
  pack_w_kernel<<<60, 256, 0, stream>>>(Wm1, Wm2, Wm1p, Wm2p);
  node_up_kernel<<<(NN*144)/256, 256, 0, stream>>>(node_feats, W_up0, W_up1, W_up2, mtab);
  hist_kernel<<<NE/256, 256, 0, stream>>>(receivers, counts);
  scan_kernel<<<1, 1024, 0, stream>>>(counts, offsets);
  scatter_kernel<<<NE/256, 256, 0, stream>>>(receivers, offsets, cursor, edge_sorted);
  find_bounds_kernel<<<NN/256, 256, 0, stream>>>(offsets, nb, NC);

  long long chunk_edges_max = NE/NC + 4096;
  int gA  = (int)((chunk_edges_max + 255)/256);
  int gSS = (NN*144 + 255)/256;
  for (int ci = 0; ci < NC; ++ci){
    edge_fused_kernel<<<gA, 256, 0, stream>>>(vectors, senders, edge_sorted,
                                              offsets, nb, Wm0, Wm1p, Wm2p,
                                              mtab, cgbuf, ci, msgb);
    seg_sum_kernel<<<gSS, 256, 0, stream>>>(offsets, nb, msgb, ci, out);
  }

  node_out_kernel<<<NN*16/256, 256, 0, stream>>>(node_feats, species,
                                                 Wd0, Wd1, Wd2, Wsk0, Wsk1, Wsk2,
                                                 out, out);
}

// Round 8
// 643.052 us; speedup vs baseline: 1.2058x; 1.2058x over previous
//
#include <hip/hip_runtime.h>
#include <math.h>

#define NN 32768
#define NE 524288

typedef __attribute__((ext_vector_type(8))) short short8v;
typedef __attribute__((ext_vector_type(4))) float f32x4;

__device__ __forceinline__ float siluf(float x){
  return x * __builtin_amdgcn_rcpf(1.0f + __expf(-x));
}

__device__ __forceinline__ unsigned short f2bf(float x){
  unsigned int b = __float_as_uint(x);
  unsigned int r = ((b >> 16) & 1u) + 0x7fffu;
  return (unsigned short)((b + r) >> 16);
}

__device__ __forceinline__ unsigned int pk2(float a, float b){
  return (unsigned int)f2bf(a) | ((unsigned int)f2bf(b) << 16);
}

__device__ const int d_PL1[11] = {0,1,2,0,1,1,2,0,1,2,2};
__device__ const int d_PL2[11] = {0,1,2,1,0,2,1,2,1,0,2};
__device__ const int d_PL3[11] = {0,0,0,1,1,1,1,2,2,2,2};

// ---------------------------------------------------------------------------
// CG math (1/PATH_NORM folded). All paths have even l1+l2+l3 -> real part.
// ---------------------------------------------------------------------------
__device__ double factd(int n){ double r=1.0; for(int i=2;i<=n;++i) r*=(double)i; return r; }

__device__ double su2_elem(int l1,int l2,int l3,int m1,int m2){
  int m3=m1+m2;
  if (m3 < -l3 || m3 > l3) return 0.0;
  double pref = sqrt((double)(2*l3+1)*factd(l3+l1-l2)*factd(l3-l1+l2)*factd(l1+l2-l3)/factd(l1+l2+l3+1));
  pref *= sqrt(factd(l3+m3)*factd(l3-m3)*factd(l1-m1)*factd(l1+m1)*factd(l2-m2)*factd(l2+m2));
  double s=0.0;
  for (int k=0;k<=l1+l2-l3;++k){
    int t1=l1+l2-l3-k, t2=l1-m1-k, t3=l2+m2-k, t4=l3-l2+m1+k, t5=l3-l1-m2+k;
    if (t1<0||t2<0||t3<0||t4<0||t5<0) continue;
    double d = factd(k)*factd(t1)*factd(t2)*factd(t3)*factd(t4)*factd(t5);
    s += ((k&1)? -1.0:1.0)/d;
  }
  return pref*s;
}

__device__ void q_elem(int l,int a,int i,double& re,double& im){
  re=0.0; im=0.0;
  const double is2 = 0.7071067811865476;
  int m = a - l;
  if (m==0){ if (i==l) re=1.0; return; }
  if (m>0){
    if (i==l+m)      re = (m&1)? -is2: is2;
    else if (i==l-m) re = is2;
  } else {
    int mm=-m;
    if (i==l-mm)      im = is2;
    else if (i==l+mm) im = (mm&1)? is2 : -is2;
  }
}

// ---------------------------------------------------------------------------
// init kernel: blocks 0..10 = CG table; blocks 11..70 = weight packing.
// ---------------------------------------------------------------------------
__global__ void init_kernel(const float* __restrict__ Wm1,
                            const float* __restrict__ Wm2,
                            float* __restrict__ cgout,
                            unsigned short* __restrict__ Wm1p,
                            unsigned short* __restrict__ Wm2p)
{
  if (blockIdx.x < 11){
    int p = blockIdx.x;
    int t = threadIdx.x;
    if (t >= 125) return;
    int a = t/25, b = (t/5)%5, c = t%5;
    int l1=d_PL1[p], l2=d_PL2[p], l3=d_PL3[p];
    int n1=2*l1+1, n2=2*l2+1, n3=2*l3+1;
    float outv = 0.0f;
    if (a<n1 && b<n2 && c<n3){
      double acc = 0.0;
      for (int i=0;i<n1;++i)
        for (int j=0;j<n2;++j){
          int m1=i-l1, m2=j-l2;
          int m3=m1+m2;
          if (m3 < -l3 || m3 > l3) continue;
          double cv = su2_elem(l1,l2,l3,m1,m2);
          if (cv==0.0) continue;
          int k = m3 + l3;
          double a1r,a1i,a2r,a2i,a3r,a3i;
          q_elem(l1,a,i,a1r,a1i);
          q_elem(l2,b,j,a2r,a2i);
          q_elem(l3,c,k,a3r,a3i);
          double re = (a1r*a2r - a1i*a2i)*a3r + (a1r*a2i + a1i*a2r)*a3i;
          acc += cv*re;
        }
      double invn = (l3==0)? 0.5773502691896258 : 0.5;
      outv = (float)(acc*invn);
    }
    cgout[p*125 + (a*5+b)*5 + c] = outv;
  } else {
    int t = (blockIdx.x - 11)*256 + threadIdx.x;
    if (t < 4096){
      int j = t & 7, lane = (t>>3)&63, ks = (t>>9)&1, ni = t>>10;
      int k = ks*32 + (lane>>4)*8 + j;
      int col = ni*16 + (lane&15);
      Wm1p[t] = f2bf(Wm1[k*64+col]);
    }
    int t2 = t - 4096;
    if (t2 >= 0 && t2 < 11264){
      int j = t2 & 7, lane = (t2>>3)&63, ks = (t2>>9)&1, ni = t2>>10;
      int k = ks*32 + (lane>>4)*8 + j;
      int col = ni*16 + (lane&15);
      Wm2p[t2] = f2bf(Wm2[k*176+col]);
    }
  }
}

// ---------------------------------------------------------------------------
// Node up-projection, iu-major layout (scaled 0.25):
// mtab row: [0:16]=m0 ch; [16:64]=m1 as [iu][16ch]; [64:144]=m2 as [iu][16ch]
// ---------------------------------------------------------------------------
__global__ __launch_bounds__(256) void node_up_kernel(
    const float* __restrict__ nf,
    const float* __restrict__ W0,
    const float* __restrict__ W1,
    const float* __restrict__ W2,
    float* __restrict__ mtab)
{
  int gidx = blockIdx.x*256 + threadIdx.x;
  if (gidx >= NN*144) return;
  int n = gidx/144;
  int col = gidx - n*144;
  const float* f = nf + (size_t)n*144;
  float acc = 0.f;
  if (col < 16){
    int o = col;
    #pragma unroll
    for (int c=0;c<16;++c) acc += f[c]*W0[c*16+o];
  } else if (col < 64){
    int idx = col-16;
    int iu = idx >> 4, o = idx & 15;
    #pragma unroll
    for (int c=0;c<16;++c) acc += f[16+c*3+iu]*W1[c*16+o];
  } else {
    int idx = col-64;
    int iu = idx >> 4, o = idx & 15;
    #pragma unroll
    for (int c=0;c<16;++c) acc += f[64+c*5+iu]*W2[c*16+o];
  }
  mtab[gidx] = 0.25f*acc;
}

// ---------------------------------------------------------------------------
// CSR build
// ---------------------------------------------------------------------------
__global__ __launch_bounds__(256) void hist_kernel(
    const int* __restrict__ recv, int* __restrict__ counts)
{
  int e = blockIdx.x*256 + threadIdx.x;
  if (e < NE) atomicAdd(&counts[recv[e]], 1);
}

// scan + chunk-bound finding (boundaries rounded to multiples of 16)
__global__ __launch_bounds__(1024) void scan_kernel(
    const int* __restrict__ counts, int* __restrict__ offsets,
    int* __restrict__ nb, int NC)
{
  __shared__ int part[1024];
  int t = threadIdx.x;
  int local[32];
  int s = 0;
  #pragma unroll
  for (int i=0;i<32;++i){ local[i]=counts[t*32+i]; s+=local[i]; }
  part[t]=s;
  __syncthreads();
  for (int off=1; off<1024; off<<=1){
    int v = (t>=off)? part[t-off] : 0;
    __syncthreads();
    part[t] += v;
    __syncthreads();
  }
  int base = part[t] - s;
  int run = base;
  #pragma unroll
  for (int i=0;i<32;++i){ offsets[t*32+i]=run; run+=local[i]; }
  if (t==1023) offsets[NN]=run;

  // chunk boundaries
  for (int i=1; i<NC; ++i){
    long long Ti = (long long)NE*i/NC;
    if ((long long)base <= Ti && Ti < (long long)part[t]){
      int run2 = base;
      #pragma unroll
      for (int k=0;k<32;++k){
        int nxt = run2 + local[k];
        if (run2 <= Ti && Ti < nxt){
          int n = t*32 + k;
          int v = ((n+1+15)>>4)<<4;
          if (v > NN) v = NN;
          nb[i] = v;
        }
        run2 = nxt;
      }
    }
  }
  if (t==0) nb[0]=0;
  if (t==1023) nb[NC]=NN;
}

__global__ __launch_bounds__(256) void scatter_kernel(
    const int* __restrict__ recv, const int* __restrict__ offsets,
    int* __restrict__ cursor, int* __restrict__ edge_sorted)
{
  int e = blockIdx.x*256 + threadIdx.x;
  if (e < NE){
    int r = recv[e];
    int pos = atomicAdd(&cursor[r], 1);
    edge_sorted[offsets[r] + pos] = e;
  }
}

// ---------------------------------------------------------------------------
// Edge MLP + mix with MFMA (R6 structure, plane-layout mixb output).
// ---------------------------------------------------------------------------
__global__ __launch_bounds__(256) void edge_mix_kernel(
    const float* __restrict__ vectors,
    const int* __restrict__ edge_sorted,
    const int* __restrict__ offsets,
    const int* __restrict__ nb,
    const float* __restrict__ Wm0,
    const unsigned short* __restrict__ Wm1p,
    const unsigned short* __restrict__ Wm2p,
    int ci, int plane_stride,
    unsigned short* __restrict__ mixb)
{
  __shared__ unsigned short lds_h[4][8*64*8];
  __shared__ float lds_s[4][64];

  int sbase = offsets[nb[ci]];
  int nE = offsets[nb[ci+1]] - sbase;
  int tid = threadIdx.x;
  int wid = tid >> 6;
  int lane = tid & 63;
  int g = lane >> 4;
  int l15 = lane & 15;
  int wb = blockIdx.x*256 + wid*64;
  int slot = wb + lane;

  float vx=0.f, vy=0.f, vz=0.f;
  if (slot < nE){
    int e = edge_sorted[sbase + slot];
    vx = vectors[(size_t)e*3+0];
    vy = vectors[(size_t)e*3+1];
    vz = vectors[(size_t)e*3+2];
  }
  float r = sqrtf(vx*vx + vy*vy + vz*vz);
  float safe = (r > 1e-9f) ? r : 1.0f;
  float inv_safe = 1.0f/safe;

  const float PIf = 3.14159265358979f;
  float xc = fminf(r*0.25f, 1.0f);
  float s1 = __sinf(PIf*xc);
  float c1 = __cosf(PIf*xc);
  float env = 0.5f*(c1 + 1.0f);
  float pref = 0.70710678118f * env * inv_safe;
  float rb[8];
  {
    float sk=s1, ck=c1;
    rb[0]=pref*sk;
    #pragma unroll
    for (int k=1;k<8;++k){
      float sn = sk*c1 + ck*s1;
      float cn = ck*c1 - sk*s1;
      sk=sn; ck=cn;
      rb[k]=pref*sk;
    }
  }

  float h[64];
  #pragma unroll
  for (int o=0;o<64;++o) h[o]=0.f;
  #pragma unroll
  for (int i=0;i<8;++i){
    float ri = rb[i];
    #pragma unroll
    for (int o=0;o<64;++o) h[o] += ri*Wm0[i*64+o];
  }

  unsigned short* Lh = lds_h[wid];
  #pragma unroll
  for (int c=0;c<8;++c){
    union { unsigned int u[4]; short8v v; } pk;
    #pragma unroll
    for (int w=0;w<4;++w){
      float a0 = siluf(h[c*8+2*w  ]*0.3535533906f);
      float a1 = siluf(h[c*8+2*w+1]*0.3535533906f);
      pk.u[w] = pk2(a0, a1);
    }
    *(short8v*)(Lh + ((size_t)(c*64 + lane))*8) = pk.v;
  }
  lds_s[wid][lane] = (r == 0.0f) ? 0.0f : 0.125f;

  __syncthreads();

  short8v a[8];
  #pragma unroll
  for (int mi=0;mi<4;++mi){
    #pragma unroll
    for (int ks=0;ks<2;++ks)
      a[mi*2+ks] = *(short8v*)(Lh + ((size_t)((ks*4+g)*64 + mi*16 + l15))*8);
  }
  #pragma unroll 1
  for (int ni=0;ni<4;++ni){
    short8v b0 = *(short8v*)(Wm1p + ((size_t)((ni*2+0)*64 + lane))*8);
    short8v b1 = *(short8v*)(Wm1p + ((size_t)((ni*2+1)*64 + lane))*8);
    int chnk = ni*2 + (l15>>3);
    int cb = l15 & 7;
    #pragma unroll
    for (int mi=0;mi<4;++mi){
      f32x4 acc = {0.f,0.f,0.f,0.f};
      acc = __builtin_amdgcn_mfma_f32_16x16x32_bf16(a[mi*2+0], b0, acc, 0,0,0);
      acc = __builtin_amdgcn_mfma_f32_16x16x32_bf16(a[mi*2+1], b1, acc, 0,0,0);
      #pragma unroll
      for (int reg=0;reg<4;++reg){
        int row = mi*16 + g*4 + reg;
        Lh[((size_t)(chnk*64 + row))*8 + cb] = f2bf(siluf(acc[reg]*0.125f));
      }
    }
  }

  short8v a2[8];
  #pragma unroll
  for (int mi=0;mi<4;++mi){
    #pragma unroll
    for (int ks=0;ks<2;++ks)
      a2[mi*2+ks] = *(short8v*)(Lh + ((size_t)((ks*4+g)*64 + mi*16 + l15))*8);
  }
  f32x4 scv[4];
  #pragma unroll
  for (int mi=0;mi<4;++mi)
    scv[mi] = *(f32x4*)(&lds_s[wid][mi*16 + g*4]);

  #pragma unroll 1
  for (int ni=0;ni<11;++ni){
    short8v b0 = *(short8v*)(Wm2p + ((size_t)((ni*2+0)*64 + lane))*8);
    short8v b1 = *(short8v*)(Wm2p + ((size_t)((ni*2+1)*64 + lane))*8);
    #pragma unroll
    for (int mi=0;mi<4;++mi){
      f32x4 acc = {0.f,0.f,0.f,0.f};
      acc = __builtin_amdgcn_mfma_f32_16x16x32_bf16(a2[mi*2+0], b0, acc, 0,0,0);
      acc = __builtin_amdgcn_mfma_f32_16x16x32_bf16(a2[mi*2+1], b1, acc, 0,0,0);
      #pragma unroll
      for (int reg=0;reg<4;++reg){
        int row = mi*16 + g*4 + reg;
        int sl = wb + row;
        if (sl < nE)
          mixb[((size_t)ni*plane_stride + sl)*16 + l15] = f2bf(acc[reg]*scv[mi][reg]);
      }
    }
  }
}

// ---------------------------------------------------------------------------
// Fused tensor-product + aggregation: block = 16 receiver nodes, LDS accum,
// edge-parallel (4 threads/edge), LDS float atomics, coalesced final store.
// ---------------------------------------------------------------------------
template<int PIDX,int L1,int L2,int L3>
__device__ __forceinline__ void do_path4(
    const float* __restrict__ cgtab,
    const unsigned short* __restrict__ mixb,
    size_t slot, size_t plane_stride, int c0,
    const float (&y1)[3], const float (&y2)[5],
    const float (&x0)[4], const float (&x1)[3][4], const float (&x2)[5][4],
    float (&msg0)[4], float (&msg1)[4][3], float (&msg2)[4][5])
{
  constexpr int d1=2*L1+1, d2=2*L2+1, d3=2*L3+1;
  const float* cgp = cgtab + PIDX*125;

  float yv[d2];
  if constexpr (L2==0){ yv[0]=1.0f; }
  else if constexpr (L2==1){ yv[0]=y1[0]; yv[1]=y1[1]; yv[2]=y1[2]; }
  else {
    #pragma unroll
    for (int j=0;j<5;++j) yv[j]=y2[j];
  }

  float M[d1][d3];
  #pragma unroll
  for (int iu=0;iu<d1;++iu){
    #pragma unroll
    for (int k=0;k<d3;++k){
      float acc = 0.f;
      #pragma unroll
      for (int j=0;j<d2;++j) acc += yv[j]*cgp[(iu*5+j)*5+k];
      M[iu][k]=acc;
    }
  }

  const unsigned short* mp = mixb + ((size_t)PIDX*plane_stride + slot)*16 + c0;
  uint2 um = *(const uint2*)mp;
  float mx[4];
  mx[0] = __uint_as_float(um.x << 16);
  mx[1] = __uint_as_float(um.x & 0xffff0000u);
  mx[2] = __uint_as_float(um.y << 16);
  mx[3] = __uint_as_float(um.y & 0xffff0000u);

  #pragma unroll
  for (int c=0;c<4;++c){
    #pragma unroll
    for (int k=0;k<d3;++k){
      float t = 0.f;
      #pragma unroll
      for (int iu=0;iu<d1;++iu){
        float xv = (L1==0)? x0[c] : (L1==1? x1[iu][c] : x2[iu][c]);
        t += xv*M[iu][k];
      }
      if constexpr (L3==0)      msg0[c]    += mx[c]*t;
      else if constexpr (L3==1) msg1[c][k] += mx[c]*t;
      else                      msg2[c][k] += mx[c]*t;
    }
  }
}

__global__ __launch_bounds__(256) void tp_agg_kernel(
    const float* __restrict__ vectors,
    const int* __restrict__ senders,
    const int* __restrict__ receivers,
    const int* __restrict__ edge_sorted,
    const int* __restrict__ offsets,
    const int* __restrict__ nb,
    const float* __restrict__ mtab,
    const float* __restrict__ cgtab,
    const unsigned short* __restrict__ mixb,
    int ci, int plane_stride,
    float* __restrict__ out)
{
  __shared__ float accum[16*144];

  int n0 = blockIdx.x*16;
  int nlo = nb[ci], nhi = nb[ci+1];
  if (n0 < nlo || n0 >= nhi) return;

  int tid = threadIdx.x;
  for (int i=tid; i<16*144; i+=256) accum[i]=0.f;
  __syncthreads();

  int cbase = offsets[nlo];
  int j0 = offsets[n0];
  int j1 = offsets[n0+16];

  const float SQ3  = 1.73205080757f;
  const float SQ15 = 3.87298334621f;
  int q = tid & 3;
  int c0 = q*4;

  for (int js=j0; js<j1; js+=64){
    int jp = js + (tid>>2);
    if (jp < j1){
      int e = edge_sorted[jp];
      int nl = receivers[e] - n0;
      float vx = vectors[(size_t)e*3+0];
      float vy = vectors[(size_t)e*3+1];
      float vz = vectors[(size_t)e*3+2];
      float r = sqrtf(vx*vx + vy*vy + vz*vz);
      float safe = (r > 1e-9f) ? r : 1.0f;
      float inv_safe = 1.0f/safe;
      float ux=vx*inv_safe, uy=vy*inv_safe, uz=vz*inv_safe;

      float y1[3] = { SQ3*uy, SQ3*uz, SQ3*ux };
      float y2[5] = { SQ15*ux*uy, SQ15*uy*uz, 1.11803398875f*(3.f*uz*uz-1.f),
                      SQ15*ux*uz, 1.93649167310f*(ux*ux-uy*uy) };

      const float* xp = mtab + (size_t)senders[e]*144;
      float x0[4];
      float x1[3][4];
      float x2[5][4];
      *(f32x4*)x0 = *(const f32x4*)(xp + c0);
      #pragma unroll
      for (int iu=0;iu<3;++iu)
        *(f32x4*)(x1[iu]) = *(const f32x4*)(xp + 16 + iu*16 + c0);
      #pragma unroll
      for (int iu=0;iu<5;++iu)
        *(f32x4*)(x2[iu]) = *(const f32x4*)(xp + 64 + iu*16 + c0);

      float msg0[4];
      float msg1[4][3];
      float msg2[4][5];
      #pragma unroll
      for (int c=0;c<4;++c){
        msg0[c]=0.f;
        #pragma unroll
        for (int i=0;i<3;++i) msg1[c][i]=0.f;
        #pragma unroll
        for (int i=0;i<5;++i) msg2[c][i]=0.f;
      }

      size_t sl = (size_t)(jp - cbase);
      do_path4< 0,0,0,0>(cgtab,mixb,sl,plane_stride,c0,y1,y2,x0,x1,x2,msg0,msg1,msg2);
      do_path4< 1,1,1,0>(cgtab,mixb,sl,plane_stride,c0,y1,y2,x0,x1,x2,msg0,msg1,msg2);
      do_path4< 2,2,2,0>(cgtab,mixb,sl,plane_stride,c0,y1,y2,x0,x1,x2,msg0,msg1,msg2);
      do_path4< 3,0,1,1>(cgtab,mixb,sl,plane_stride,c0,y1,y2,x0,x1,x2,msg0,msg1,msg2);
      do_path4< 4,1,0,1>(cgtab,mixb,sl,plane_stride,c0,y1,y2,x0,x1,x2,msg0,msg1,msg2);
      do_path4< 5,1,2,1>(cgtab,mixb,sl,plane_stride,c0,y1,y2,x0,x1,x2,msg0,msg1,msg2);
      do_path4< 6,2,1,1>(cgtab,mixb,sl,plane_stride,c0,y1,y2,x0,x1,x2,msg0,msg1,msg2);
      do_path4< 7,0,2,2>(cgtab,mixb,sl,plane_stride,c0,y1,y2,x0,x1,x2,msg0,msg1,msg2);
      do_path4< 8,1,1,2>(cgtab,mixb,sl,plane_stride,c0,y1,y2,x0,x1,x2,msg0,msg1,msg2);
      do_path4< 9,2,0,2>(cgtab,mixb,sl,plane_stride,c0,y1,y2,x0,x1,x2,msg0,msg1,msg2);
      do_path4<10,2,2,2>(cgtab,mixb,sl,plane_stride,c0,y1,y2,x0,x1,x2,msg0,msg1,msg2);

      float* an = accum + nl*144;
      #pragma unroll
      for (int c=0;c<4;++c) atomicAdd(&an[c0+c], msg0[c]);
      #pragma unroll
      for (int c=0;c<4;++c){
        #pragma unroll
        for (int i=0;i<3;++i) atomicAdd(&an[16 + (c0+c)*3 + i], msg1[c][i]);
      }
      #pragma unroll
      for (int c=0;c<4;++c){
        #pragma unroll
        for (int i=0;i<5;++i) atomicAdd(&an[64 + (c0+c)*5 + i], msg2[c][i]);
      }
    }
  }

  __syncthreads();
  float* ob = out + (size_t)n0*144;
  for (int i=tid; i<16*144; i+=256) ob[i] = accum[i];
}

// ---------------------------------------------------------------------------
// Final node update, in-place on out.
// ---------------------------------------------------------------------------
__global__ __launch_bounds__(256) void node_out_kernel(
    const float* __restrict__ nf,
    const int* __restrict__ species,
    const float* __restrict__ Wd0,
    const float* __restrict__ Wd1,
    const float* __restrict__ Wd2,
    const float* __restrict__ Wsk0,
    const float* __restrict__ Wsk1,
    const float* __restrict__ Wsk2,
    const float* agg,
    float* out)
{
  int t = blockIdx.x*256 + threadIdx.x;
  int n = t >> 4;
  int o = t & 15;
  if (n >= NN) return;
  const float* an = agg + (size_t)n*144;
  const float* f  = nf  + (size_t)n*144;
  int sp = species[n];
  const float* wk0 = Wsk0 + sp*768;
  const float* wk1 = Wsk1 + sp*256;
  const float* wk2 = Wsk2 + sp*256;

  float sa0=0,sa1=0,sa2=0, sf0=0,sf1=0,sf2=0;
  #pragma unroll
  for (int c=0;c<16;++c){
    float aa = an[c], ff = f[c];
    sa0 += aa*Wd0[c*48+o];
    sa1 += aa*Wd0[c*48+16+o];
    sa2 += aa*Wd0[c*48+32+o];
    sf0 += ff*wk0[c*48+o];
    sf1 += ff*wk0[c*48+16+o];
    sf2 += ff*wk0[c*48+32+o];
  }
  float s0 = 0.0625f*sa0 + 0.25f*sf0;
  float s1 = 0.0625f*sa1 + 0.25f*sf1;
  float s2 = 0.0625f*sa2 + 0.25f*sf2;
  float scvv = siluf(s0);
  float g1  = siluf(s1);
  float g2  = siluf(s2);

  float v[3];
  #pragma unroll
  for (int i=0;i<3;++i){
    float av=0, fv=0;
    #pragma unroll
    for (int c=0;c<16;++c){
      av += an[16+c*3+i]*Wd1[c*16+o];
      fv += f[16+c*3+i]*wk1[c*16+o];
    }
    v[i] = (0.0625f*av + 0.25f*fv)*g1;
  }
  float q[5];
  #pragma unroll
  for (int i=0;i<5;++i){
    float av=0, fv=0;
    #pragma unroll
    for (int c=0;c<16;++c){
      av += an[64+c*5+i]*Wd2[c*16+o];
      fv += f[64+c*5+i]*wk2[c*16+o];
    }
    q[i] = (0.0625f*av + 0.25f*fv)*g2;
  }

  float* on = out + (size_t)n*144;
  on[o] = scvv;
  #pragma unroll
  for (int i=0;i<3;++i) on[16+o*3+i] = v[i];
  #pragma unroll
  for (int i=0;i<5;++i) on[64+o*5+i] = q[i];
}

// ---------------------------------------------------------------------------
extern "C" void kernel_launch(void* const* d_in, const int* in_sizes, int n_in,
                              void* d_out, int out_size, void* d_ws, size_t ws_size,
                              hipStream_t stream)
{
  const float* vectors    = (const float*)d_in[0];
  const float* node_feats = (const float*)d_in[1];
  const int*   species    = (const int*)d_in[2];
  const int*   senders    = (const int*)d_in[3];
  const int*   receivers  = (const int*)d_in[4];
  const float* W_up0 = (const float*)d_in[5];
  const float* W_up1 = (const float*)d_in[6];
  const float* W_up2 = (const float*)d_in[7];
  const float* Wm0   = (const float*)d_in[8];
  const float* Wm1   = (const float*)d_in[9];
  const float* Wm2   = (const float*)d_in[10];
  const float* Wd0   = (const float*)d_in[11];
  const float* Wd1   = (const float*)d_in[12];
  const float* Wd2   = (const float*)d_in[13];
  const float* Wsk0  = (const float*)d_in[14];
  const float* Wsk1  = (const float*)d_in[15];
  const float* Wsk2  = (const float*)d_in[16];
  float* out = (float*)d_out;
  float* ws  = (float*)d_ws;

  // ws layout (float units):
  // [cg 2048][mtab NN*144][counts NN][cursor NN][offsets NN+64][edge_sorted NE]
  // [nb 16][Wm1p 2048][Wm2p 5632][mixb bf16 planes]
  float* cgbuf = ws;
  float* mtab  = ws + 2048;
  int* counts      = (int*)(ws + 2048 + (size_t)NN*144);
  int* cursor      = counts + NN;
  int* offsets     = cursor + NN;
  int* edge_sorted = offsets + NN + 64;
  int* nb          = edge_sorted + NE;
  unsigned short* Wm1p = (unsigned short*)(nb + 16);
  unsigned short* Wm2p = Wm1p + 4096;
  unsigned short* mixb = Wm2p + 11264;

  size_t fixed_f = 2048 + (size_t)NN*144 + NN + NN + (NN+64) + NE + 16 + 2048 + 5632;
  size_t ws_f = ws_size/4;
  // per-edge ws need: mixb 176 bf16 = 88 floats
  long long cap_rows = (ws_f > fixed_f) ? (long long)((ws_f - fixed_f)/88) : 0;
  long long capm = cap_rows - 8192;
  if (capm < 16384) capm = 16384;
  int NC = (int)((NE + capm - 1)/capm);
  if (NC < 1) NC = 1;
  if (NC > 15) NC = 15;
  int plane_stride = (int)(NE/NC + 4096);

  hipMemsetAsync(counts, 0, 2*(size_t)NN*sizeof(int), stream);
  init_kernel<<<71, 256, 0, stream>>>(Wm1, Wm2, cgbuf, Wm1p, Wm2p);
  node_up_kernel<<<(NN*144)/256, 256, 0, stream>>>(node_feats, W_up0, W_up1, W_up2, mtab);
  hist_kernel<<<NE/256, 256, 0, stream>>>(receivers, counts);
  scan_kernel<<<1, 1024, 0, stream>>>(counts, offsets, nb, NC);
  scatter_kernel<<<NE/256, 256, 0, stream>>>(receivers, offsets, cursor, edge_sorted);

  long long chunk_edges_max = NE/NC + 4096;
  int gA   = (int)((chunk_edges_max + 255)/256);
  int gAgg = NN/16;
  for (int ci = 0; ci < NC; ++ci){
    edge_mix_kernel<<<gA, 256, 0, stream>>>(vectors, edge_sorted, offsets, nb,
                                            Wm0, Wm1p, Wm2p, ci, plane_stride, mixb);
    tp_agg_kernel<<<gAgg, 256, 0, stream>>>(vectors, senders, receivers,
                                            edge_sorted, offsets, nb, mtab,
                                            cgbuf, mixb, ci, plane_stride, out);
  }

  node_out_kernel<<<NN*16/256, 256, 0, stream>>>(node_feats, species,
                                                 Wd0, Wd1, Wd2, Wsk0, Wsk1, Wsk2,
                                                 out, out);
}

// Round 9
// 472.127 us; speedup vs baseline: 1.6423x; 1.3620x over previous
//
#include <hip/hip_runtime.h>
#include <math.h>

#define NN 32768
#define NE 524288

typedef __attribute__((ext_vector_type(8))) short short8v;
typedef __attribute__((ext_vector_type(4))) float f32x4;

__device__ __forceinline__ float siluf(float x){
  return x * __builtin_amdgcn_rcpf(1.0f + __expf(-x));
}

__device__ __forceinline__ unsigned short f2bf(float x){
  unsigned int b = __float_as_uint(x);
  unsigned int r = ((b >> 16) & 1u) + 0x7fffu;
  return (unsigned short)((b + r) >> 16);
}

__device__ __forceinline__ unsigned int pk2(float a, float b){
  return (unsigned int)f2bf(a) | ((unsigned int)f2bf(b) << 16);
}

__device__ __forceinline__ float bf2f(unsigned short v){
  return __uint_as_float(((unsigned int)v) << 16);
}

__device__ const int d_PL1[11] = {0,1,2,0,1,1,2,0,1,2,2};
__device__ const int d_PL2[11] = {0,1,2,1,0,2,1,2,1,0,2};
__device__ const int d_PL3[11] = {0,0,0,1,1,1,1,2,2,2,2};

// ---------------------------------------------------------------------------
// CG math (1/PATH_NORM folded). All paths have even l1+l2+l3 -> real part.
// ---------------------------------------------------------------------------
__device__ double factd(int n){ double r=1.0; for(int i=2;i<=n;++i) r*=(double)i; return r; }

__device__ double su2_elem(int l1,int l2,int l3,int m1,int m2){
  int m3=m1+m2;
  if (m3 < -l3 || m3 > l3) return 0.0;
  double pref = sqrt((double)(2*l3+1)*factd(l3+l1-l2)*factd(l3-l1+l2)*factd(l1+l2-l3)/factd(l1+l2+l3+1));
  pref *= sqrt(factd(l3+m3)*factd(l3-m3)*factd(l1-m1)*factd(l1+m1)*factd(l2-m2)*factd(l2+m2));
  double s=0.0;
  for (int k=0;k<=l1+l2-l3;++k){
    int t1=l1+l2-l3-k, t2=l1-m1-k, t3=l2+m2-k, t4=l3-l2+m1+k, t5=l3-l1-m2+k;
    if (t1<0||t2<0||t3<0||t4<0||t5<0) continue;
    double d = factd(k)*factd(t1)*factd(t2)*factd(t3)*factd(t4)*factd(t5);
    s += ((k&1)? -1.0:1.0)/d;
  }
  return pref*s;
}

__device__ void q_elem(int l,int a,int i,double& re,double& im){
  re=0.0; im=0.0;
  const double is2 = 0.7071067811865476;
  int m = a - l;
  if (m==0){ if (i==l) re=1.0; return; }
  if (m>0){
    if (i==l+m)      re = (m&1)? -is2: is2;
    else if (i==l-m) re = is2;
  } else {
    int mm=-m;
    if (i==l-mm)      im = is2;
    else if (i==l+mm) im = (mm&1)? is2 : -is2;
  }
}

// ---------------------------------------------------------------------------
// init kernel: blocks 0..10 = CG table; blocks 11..70 = weight packing.
// ---------------------------------------------------------------------------
__global__ void init_kernel(const float* __restrict__ Wm1,
                            const float* __restrict__ Wm2,
                            float* __restrict__ cgout,
                            unsigned short* __restrict__ Wm1p,
                            unsigned short* __restrict__ Wm2p)
{
  if (blockIdx.x < 11){
    int p = blockIdx.x;
    int t = threadIdx.x;
    if (t >= 125) return;
    int a = t/25, b = (t/5)%5, c = t%5;
    int l1=d_PL1[p], l2=d_PL2[p], l3=d_PL3[p];
    int n1=2*l1+1, n2=2*l2+1, n3=2*l3+1;
    float outv = 0.0f;
    if (a<n1 && b<n2 && c<n3){
      double acc = 0.0;
      for (int i=0;i<n1;++i)
        for (int j=0;j<n2;++j){
          int m1=i-l1, m2=j-l2;
          int m3=m1+m2;
          if (m3 < -l3 || m3 > l3) continue;
          double cv = su2_elem(l1,l2,l3,m1,m2);
          if (cv==0.0) continue;
          int k = m3 + l3;
          double a1r,a1i,a2r,a2i,a3r,a3i;
          q_elem(l1,a,i,a1r,a1i);
          q_elem(l2,b,j,a2r,a2i);
          q_elem(l3,c,k,a3r,a3i);
          double re = (a1r*a2r - a1i*a2i)*a3r + (a1r*a2i + a1i*a2r)*a3i;
          acc += cv*re;
        }
      double invn = (l3==0)? 0.5773502691896258 : 0.5;
      outv = (float)(acc*invn);
    }
    cgout[p*125 + (a*5+b)*5 + c] = outv;
  } else {
    int t = (blockIdx.x - 11)*256 + threadIdx.x;
    if (t < 4096){
      int j = t & 7, lane = (t>>3)&63, ks = (t>>9)&1, ni = t>>10;
      int k = ks*32 + (lane>>4)*8 + j;
      int col = ni*16 + (lane&15);
      Wm1p[t] = f2bf(Wm1[k*64+col]);
    }
    int t2 = t - 4096;
    if (t2 >= 0 && t2 < 11264){
      int j = t2 & 7, lane = (t2>>3)&63, ks = (t2>>9)&1, ni = t2>>10;
      int k = ks*32 + (lane>>4)*8 + j;
      int col = ni*16 + (lane&15);
      Wm2p[t2] = f2bf(Wm2[k*176+col]);
    }
  }
}

// ---------------------------------------------------------------------------
// Node up-projection, iu-major layout (scaled 0.25):
// mtab row: [0:16]=m0 ch; [16:64]=m1 as [iu][16ch]; [64:144]=m2 as [iu][16ch]
// ---------------------------------------------------------------------------
__global__ __launch_bounds__(256) void node_up_kernel(
    const float* __restrict__ nf,
    const float* __restrict__ W0,
    const float* __restrict__ W1,
    const float* __restrict__ W2,
    float* __restrict__ mtab)
{
  int gidx = blockIdx.x*256 + threadIdx.x;
  if (gidx >= NN*144) return;
  int n = gidx/144;
  int col = gidx - n*144;
  const float* f = nf + (size_t)n*144;
  float acc = 0.f;
  if (col < 16){
    int o = col;
    #pragma unroll
    for (int c=0;c<16;++c) acc += f[c]*W0[c*16+o];
  } else if (col < 64){
    int idx = col-16;
    int iu = idx >> 4, o = idx & 15;
    #pragma unroll
    for (int c=0;c<16;++c) acc += f[16+c*3+iu]*W1[c*16+o];
  } else {
    int idx = col-64;
    int iu = idx >> 4, o = idx & 15;
    #pragma unroll
    for (int c=0;c<16;++c) acc += f[64+c*5+iu]*W2[c*16+o];
  }
  mtab[gidx] = 0.25f*acc;
}

// ---------------------------------------------------------------------------
// CSR build
// ---------------------------------------------------------------------------
__global__ __launch_bounds__(256) void hist_kernel(
    const int* __restrict__ recv, int* __restrict__ counts)
{
  int e = blockIdx.x*256 + threadIdx.x;
  if (e < NE) atomicAdd(&counts[recv[e]], 1);
}

__global__ __launch_bounds__(1024) void scan_kernel(
    const int* __restrict__ counts, int* __restrict__ offsets,
    int* __restrict__ nb, int NC)
{
  __shared__ int part[1024];
  int t = threadIdx.x;
  int local[32];
  int s = 0;
  #pragma unroll
  for (int i=0;i<32;++i){ local[i]=counts[t*32+i]; s+=local[i]; }
  part[t]=s;
  __syncthreads();
  for (int off=1; off<1024; off<<=1){
    int v = (t>=off)? part[t-off] : 0;
    __syncthreads();
    part[t] += v;
    __syncthreads();
  }
  int base = part[t] - s;
  int run = base;
  #pragma unroll
  for (int i=0;i<32;++i){ offsets[t*32+i]=run; run+=local[i]; }
  if (t==1023) offsets[NN]=run;

  for (int i=1; i<NC; ++i){
    long long Ti = (long long)NE*i/NC;
    if ((long long)base <= Ti && Ti < (long long)part[t]){
      int run2 = base;
      #pragma unroll
      for (int k=0;k<32;++k){
        int nxt = run2 + local[k];
        if (run2 <= Ti && Ti < nxt) nb[i] = t*32 + k + 1;
        run2 = nxt;
      }
    }
  }
  if (t==0) nb[0]=0;
  if (t==1023) nb[NC]=NN;
}

__global__ __launch_bounds__(256) void scatter_kernel(
    const int* __restrict__ recv, const int* __restrict__ offsets,
    int* __restrict__ cursor, int* __restrict__ edge_sorted)
{
  int e = blockIdx.x*256 + threadIdx.x;
  if (e < NE){
    int r = recv[e];
    int pos = atomicAdd(&cursor[r], 1);
    edge_sorted[offsets[r] + pos] = e;
  }
}

// ---------------------------------------------------------------------------
// Edge MLP + mix with MFMA (R6 structure). Also emits per-slot side data:
// ylm[slot][8] = {y1[3], y2[5]} bf16, sedge[slot] = sender id.
// mixb: plane layout [path][slot][16 ch] bf16.
// ---------------------------------------------------------------------------
__global__ __launch_bounds__(256) void edge_mix_kernel(
    const float* __restrict__ vectors,
    const int* __restrict__ senders,
    const int* __restrict__ edge_sorted,
    const int* __restrict__ offsets,
    const int* __restrict__ nb,
    const float* __restrict__ Wm0,
    const unsigned short* __restrict__ Wm1p,
    const unsigned short* __restrict__ Wm2p,
    int ci, int plane_stride,
    unsigned short* __restrict__ mixb,
    unsigned short* __restrict__ ylm,
    int* __restrict__ sedge)
{
  __shared__ unsigned short lds_h[4][8*64*8];
  __shared__ float lds_s[4][64];

  int sbase = offsets[nb[ci]];
  int nE = offsets[nb[ci+1]] - sbase;
  int tid = threadIdx.x;
  int wid = tid >> 6;
  int lane = tid & 63;
  int g = lane >> 4;
  int l15 = lane & 15;
  int wb = blockIdx.x*256 + wid*64;
  int slot = wb + lane;

  float vx=0.f, vy=0.f, vz=0.f;
  int snd = 0;
  if (slot < nE){
    int e = edge_sorted[sbase + slot];
    vx = vectors[(size_t)e*3+0];
    vy = vectors[(size_t)e*3+1];
    vz = vectors[(size_t)e*3+2];
    snd = senders[e];
  }
  float r = sqrtf(vx*vx + vy*vy + vz*vz);
  float safe = (r > 1e-9f) ? r : 1.0f;
  float inv_safe = 1.0f/safe;

  const float PIf = 3.14159265358979f;
  float xc = fminf(r*0.25f, 1.0f);
  float s1 = __sinf(PIf*xc);
  float c1 = __cosf(PIf*xc);
  float env = 0.5f*(c1 + 1.0f);
  float pref = 0.70710678118f * env * inv_safe;
  float rb[8];
  {
    float sk=s1, ck=c1;
    rb[0]=pref*sk;
    #pragma unroll
    for (int k=1;k<8;++k){
      float sn = sk*c1 + ck*s1;
      float cn = ck*c1 - sk*s1;
      sk=sn; ck=cn;
      rb[k]=pref*sk;
    }
  }

  // side data: y1/y2 bf16 + sender
  if (slot < nE){
    float ux=vx*inv_safe, uy=vy*inv_safe, uz=vz*inv_safe;
    const float SQ3  = 1.73205080757f;
    const float SQ15 = 3.87298334621f;
    union { uint4 u; unsigned short s[8]; } yv;
    yv.s[0]=f2bf(SQ3*uy);  yv.s[1]=f2bf(SQ3*uz);  yv.s[2]=f2bf(SQ3*ux);
    yv.s[3]=f2bf(SQ15*ux*uy);
    yv.s[4]=f2bf(SQ15*uy*uz);
    yv.s[5]=f2bf(1.11803398875f*(3.f*uz*uz-1.f));
    yv.s[6]=f2bf(SQ15*ux*uz);
    yv.s[7]=f2bf(1.93649167310f*(ux*ux-uy*uy));
    *(uint4*)(ylm + (size_t)slot*8) = yv.u;
    sedge[slot] = snd;
  }

  float h[64];
  #pragma unroll
  for (int o=0;o<64;++o) h[o]=0.f;
  #pragma unroll
  for (int i=0;i<8;++i){
    float ri = rb[i];
    #pragma unroll
    for (int o=0;o<64;++o) h[o] += ri*Wm0[i*64+o];
  }

  unsigned short* Lh = lds_h[wid];
  #pragma unroll
  for (int c=0;c<8;++c){
    union { unsigned int u[4]; short8v v; } pk;
    #pragma unroll
    for (int w=0;w<4;++w){
      float a0 = siluf(h[c*8+2*w  ]*0.3535533906f);
      float a1 = siluf(h[c*8+2*w+1]*0.3535533906f);
      pk.u[w] = pk2(a0, a1);
    }
    *(short8v*)(Lh + ((size_t)(c*64 + lane))*8) = pk.v;
  }
  lds_s[wid][lane] = (r == 0.0f) ? 0.0f : 0.125f;

  __syncthreads();

  short8v a[8];
  #pragma unroll
  for (int mi=0;mi<4;++mi){
    #pragma unroll
    for (int ks=0;ks<2;++ks)
      a[mi*2+ks] = *(short8v*)(Lh + ((size_t)((ks*4+g)*64 + mi*16 + l15))*8);
  }
  #pragma unroll 1
  for (int ni=0;ni<4;++ni){
    short8v b0 = *(short8v*)(Wm1p + ((size_t)((ni*2+0)*64 + lane))*8);
    short8v b1 = *(short8v*)(Wm1p + ((size_t)((ni*2+1)*64 + lane))*8);
    int chnk = ni*2 + (l15>>3);
    int cb = l15 & 7;
    #pragma unroll
    for (int mi=0;mi<4;++mi){
      f32x4 acc = {0.f,0.f,0.f,0.f};
      acc = __builtin_amdgcn_mfma_f32_16x16x32_bf16(a[mi*2+0], b0, acc, 0,0,0);
      acc = __builtin_amdgcn_mfma_f32_16x16x32_bf16(a[mi*2+1], b1, acc, 0,0,0);
      #pragma unroll
      for (int reg=0;reg<4;++reg){
        int row = mi*16 + g*4 + reg;
        Lh[((size_t)(chnk*64 + row))*8 + cb] = f2bf(siluf(acc[reg]*0.125f));
      }
    }
  }

  short8v a2[8];
  #pragma unroll
  for (int mi=0;mi<4;++mi){
    #pragma unroll
    for (int ks=0;ks<2;++ks)
      a2[mi*2+ks] = *(short8v*)(Lh + ((size_t)((ks*4+g)*64 + mi*16 + l15))*8);
  }
  f32x4 scv[4];
  #pragma unroll
  for (int mi=0;mi<4;++mi)
    scv[mi] = *(f32x4*)(&lds_s[wid][mi*16 + g*4]);

  #pragma unroll 1
  for (int ni=0;ni<11;++ni){
    short8v b0 = *(short8v*)(Wm2p + ((size_t)((ni*2+0)*64 + lane))*8);
    short8v b1 = *(short8v*)(Wm2p + ((size_t)((ni*2+1)*64 + lane))*8);
    #pragma unroll
    for (int mi=0;mi<4;++mi){
      f32x4 acc = {0.f,0.f,0.f,0.f};
      acc = __builtin_amdgcn_mfma_f32_16x16x32_bf16(a2[mi*2+0], b0, acc, 0,0,0);
      acc = __builtin_amdgcn_mfma_f32_16x16x32_bf16(a2[mi*2+1], b1, acc, 0,0,0);
      #pragma unroll
      for (int reg=0;reg<4;++reg){
        int row = mi*16 + g*4 + reg;
        int sl = wb + row;
        if (sl < nE)
          mixb[((size_t)ni*plane_stride + sl)*16 + l15] = f2bf(acc[reg]*scv[mi][reg]);
      }
    }
  }
}

// ---------------------------------------------------------------------------
// Edge-parallel tensor product, slot-indexed inputs only (no gather chains).
// Thread per (slot, channel-quad); writes msgb[slot][144] bf16.
// ---------------------------------------------------------------------------
template<int PIDX,int L1,int L2,int L3>
__device__ __forceinline__ void do_path4(
    const float* __restrict__ cgtab,
    uint2 um, int c0,
    const float (&y1)[3], const float (&y2)[5],
    const float (&x0)[4], const float (&x1)[3][4], const float (&x2)[5][4],
    float (&msg0)[4], float (&msg1)[4][3], float (&msg2)[4][5])
{
  constexpr int d1=2*L1+1, d2=2*L2+1, d3=2*L3+1;
  const float* cgp = cgtab + PIDX*125;

  float yv[d2];
  if constexpr (L2==0){ yv[0]=1.0f; }
  else if constexpr (L2==1){ yv[0]=y1[0]; yv[1]=y1[1]; yv[2]=y1[2]; }
  else {
    #pragma unroll
    for (int j=0;j<5;++j) yv[j]=y2[j];
  }

  float M[d1][d3];
  #pragma unroll
  for (int iu=0;iu<d1;++iu){
    #pragma unroll
    for (int k=0;k<d3;++k){
      float acc = 0.f;
      #pragma unroll
      for (int j=0;j<d2;++j) acc += yv[j]*cgp[(iu*5+j)*5+k];
      M[iu][k]=acc;
    }
  }

  float mx[4];
  mx[0] = __uint_as_float(um.x << 16);
  mx[1] = __uint_as_float(um.x & 0xffff0000u);
  mx[2] = __uint_as_float(um.y << 16);
  mx[3] = __uint_as_float(um.y & 0xffff0000u);

  #pragma unroll
  for (int c=0;c<4;++c){
    #pragma unroll
    for (int k=0;k<d3;++k){
      float t = 0.f;
      #pragma unroll
      for (int iu=0;iu<d1;++iu){
        float xv = (L1==0)? x0[c] : (L1==1? x1[iu][c] : x2[iu][c]);
        t += xv*M[iu][k];
      }
      if constexpr (L3==0)      msg0[c]    += mx[c]*t;
      else if constexpr (L3==1) msg1[c][k] += mx[c]*t;
      else                      msg2[c][k] += mx[c]*t;
    }
  }
}

__global__ __launch_bounds__(256) void tp_kernel(
    const int* __restrict__ offsets,
    const int* __restrict__ nb,
    const float* __restrict__ mtab,
    const float* __restrict__ cgtab,
    const unsigned short* __restrict__ mixb,
    const unsigned short* __restrict__ ylm,
    const int* __restrict__ sedge,
    int ci, int plane_stride,
    unsigned short* __restrict__ msgb)
{
  int t = blockIdx.x*256 + threadIdx.x;
  int slot = t >> 2;
  int sbase = offsets[nb[ci]];
  int nE = offsets[nb[ci+1]] - sbase;
  if (slot >= nE) return;
  int c0 = (t & 3)*4;

  // all loads upfront (independent)
  union { uint4 u; unsigned short s[8]; } yv;
  yv.u = *(const uint4*)(ylm + (size_t)slot*8);
  int snd = sedge[slot];

  uint2 um[11];
  #pragma unroll
  for (int p=0;p<11;++p)
    um[p] = *(const uint2*)(mixb + ((size_t)p*plane_stride + slot)*16 + c0);

  const float* xp = mtab + (size_t)snd*144;
  float x0[4];
  float x1[3][4];
  float x2[5][4];
  *(f32x4*)x0 = *(const f32x4*)(xp + c0);
  #pragma unroll
  for (int iu=0;iu<3;++iu)
    *(f32x4*)(x1[iu]) = *(const f32x4*)(xp + 16 + iu*16 + c0);
  #pragma unroll
  for (int iu=0;iu<5;++iu)
    *(f32x4*)(x2[iu]) = *(const f32x4*)(xp + 64 + iu*16 + c0);

  float y1[3], y2[5];
  y1[0]=bf2f(yv.s[0]); y1[1]=bf2f(yv.s[1]); y1[2]=bf2f(yv.s[2]);
  y2[0]=bf2f(yv.s[3]); y2[1]=bf2f(yv.s[4]); y2[2]=bf2f(yv.s[5]);
  y2[3]=bf2f(yv.s[6]); y2[4]=bf2f(yv.s[7]);

  float msg0[4];
  float msg1[4][3];
  float msg2[4][5];
  #pragma unroll
  for (int c=0;c<4;++c){
    msg0[c]=0.f;
    #pragma unroll
    for (int i=0;i<3;++i) msg1[c][i]=0.f;
    #pragma unroll
    for (int i=0;i<5;++i) msg2[c][i]=0.f;
  }

  do_path4< 0,0,0,0>(cgtab,um[ 0],c0,y1,y2,x0,x1,x2,msg0,msg1,msg2);
  do_path4< 1,1,1,0>(cgtab,um[ 1],c0,y1,y2,x0,x1,x2,msg0,msg1,msg2);
  do_path4< 2,2,2,0>(cgtab,um[ 2],c0,y1,y2,x0,x1,x2,msg0,msg1,msg2);
  do_path4< 3,0,1,1>(cgtab,um[ 3],c0,y1,y2,x0,x1,x2,msg0,msg1,msg2);
  do_path4< 4,1,0,1>(cgtab,um[ 4],c0,y1,y2,x0,x1,x2,msg0,msg1,msg2);
  do_path4< 5,1,2,1>(cgtab,um[ 5],c0,y1,y2,x0,x1,x2,msg0,msg1,msg2);
  do_path4< 6,2,1,1>(cgtab,um[ 6],c0,y1,y2,x0,x1,x2,msg0,msg1,msg2);
  do_path4< 7,0,2,2>(cgtab,um[ 7],c0,y1,y2,x0,x1,x2,msg0,msg1,msg2);
  do_path4< 8,1,1,2>(cgtab,um[ 8],c0,y1,y2,x0,x1,x2,msg0,msg1,msg2);
  do_path4< 9,2,0,2>(cgtab,um[ 9],c0,y1,y2,x0,x1,x2,msg0,msg1,msg2);
  do_path4<10,2,2,2>(cgtab,um[10],c0,y1,y2,x0,x1,x2,msg0,msg1,msg2);

  unsigned short* mr = msgb + (size_t)slot*144;
  {
    uint2 w;
    w.x = pk2(msg0[0], msg0[1]);
    w.y = pk2(msg0[2], msg0[3]);
    *(uint2*)(mr + c0) = w;
  }
  {
    unsigned short* p = mr + 16 + c0*3;
    uint2 w0, w1, w2;
    w0.x = pk2(msg1[0][0], msg1[0][1]);
    w0.y = pk2(msg1[0][2], msg1[1][0]);
    w1.x = pk2(msg1[1][1], msg1[1][2]);
    w1.y = pk2(msg1[2][0], msg1[2][1]);
    w2.x = pk2(msg1[2][2], msg1[3][0]);
    w2.y = pk2(msg1[3][1], msg1[3][2]);
    *(uint2*)(p) = w0;
    *(uint2*)(p+4) = w1;
    *(uint2*)(p+8) = w2;
  }
  {
    unsigned short* p = mr + 64 + c0*5;
    #pragma unroll
    for (int w=0; w<5; ++w){
      int i0 = w*4;
      float v0 = msg2[(i0+0)/5][(i0+0)%5];
      float v1 = msg2[(i0+1)/5][(i0+1)%5];
      float v2 = msg2[(i0+2)/5][(i0+2)%5];
      float v3 = msg2[(i0+3)/5][(i0+3)%5];
      uint2 ww;
      ww.x = pk2(v0, v1);
      ww.y = pk2(v2, v3);
      *(uint2*)(p + i0) = ww;
    }
  }
}

// ---------------------------------------------------------------------------
// Segmented sum over sorted msgb rows: thread per (node, col).
// ---------------------------------------------------------------------------
__global__ __launch_bounds__(256) void seg_sum_kernel(
    const int* __restrict__ offsets,
    const int* __restrict__ nb,
    const unsigned short* __restrict__ msgb,
    int ci,
    float* __restrict__ out)
{
  int t = blockIdx.x*256 + threadIdx.x;
  int n = t/144;
  int col = t - n*144;
  if (n >= NN) return;
  int nlo = nb[ci], nhi = nb[ci+1];
  if (n < nlo || n >= nhi) return;
  int cbase = offsets[nlo];
  int j0 = offsets[n] - cbase;
  int j1 = offsets[n+1] - cbase;
  float acc = 0.f;
  for (int j=j0; j<j1; ++j){
    acc += bf2f(msgb[(size_t)j*144 + col]);
  }
  out[(size_t)n*144 + col] = acc;
}

// ---------------------------------------------------------------------------
// Final node update, in-place on out.
// ---------------------------------------------------------------------------
__global__ __launch_bounds__(256) void node_out_kernel(
    const float* __restrict__ nf,
    const int* __restrict__ species,
    const float* __restrict__ Wd0,
    const float* __restrict__ Wd1,
    const float* __restrict__ Wd2,
    const float* __restrict__ Wsk0,
    const float* __restrict__ Wsk1,
    const float* __restrict__ Wsk2,
    const float* agg,
    float* out)
{
  int t = blockIdx.x*256 + threadIdx.x;
  int n = t >> 4;
  int o = t & 15;
  if (n >= NN) return;
  const float* an = agg + (size_t)n*144;
  const float* f  = nf  + (size_t)n*144;
  int sp = species[n];
  const float* wk0 = Wsk0 + sp*768;
  const float* wk1 = Wsk1 + sp*256;
  const float* wk2 = Wsk2 + sp*256;

  float sa0=0,sa1=0,sa2=0, sf0=0,sf1=0,sf2=0;
  #pragma unroll
  for (int c=0;c<16;++c){
    float aa = an[c], ff = f[c];
    sa0 += aa*Wd0[c*48+o];
    sa1 += aa*Wd0[c*48+16+o];
    sa2 += aa*Wd0[c*48+32+o];
    sf0 += ff*wk0[c*48+o];
    sf1 += ff*wk0[c*48+16+o];
    sf2 += ff*wk0[c*48+32+o];
  }
  float s0 = 0.0625f*sa0 + 0.25f*sf0;
  float s1 = 0.0625f*sa1 + 0.25f*sf1;
  float s2 = 0.0625f*sa2 + 0.25f*sf2;
  float scvv = siluf(s0);
  float g1  = siluf(s1);
  float g2  = siluf(s2);

  float v[3];
  #pragma unroll
  for (int i=0;i<3;++i){
    float av=0, fv=0;
    #pragma unroll
    for (int c=0;c<16;++c){
      av += an[16+c*3+i]*Wd1[c*16+o];
      fv += f[16+c*3+i]*wk1[c*16+o];
    }
    v[i] = (0.0625f*av + 0.25f*fv)*g1;
  }
  float q[5];
  #pragma unroll
  for (int i=0;i<5;++i){
    float av=0, fv=0;
    #pragma unroll
    for (int c=0;c<16;++c){
      av += an[64+c*5+i]*Wd2[c*16+o];
      fv += f[64+c*5+i]*wk2[c*16+o];
    }
    q[i] = (0.0625f*av + 0.25f*fv)*g2;
  }

  float* on = out + (size_t)n*144;
  on[o] = scvv;
  #pragma unroll
  for (int i=0;i<3;++i) on[16+o*3+i] = v[i];
  #pragma unroll
  for (int i=0;i<5;++i) on[64+o*5+i] = q[i];
}

// ---------------------------------------------------------------------------
extern "C" void kernel_launch(void* const* d_in, const int* in_sizes, int n_in,
                              void* d_out, int out_size, void* d_ws, size_t ws_size,
                              hipStream_t stream)
{
  const float* vectors    = (const float*)d_in[0];
  const float* node_feats = (const float*)d_in[1];
  const int*   species    = (const int*)d_in[2];
  const int*   senders    = (const int*)d_in[3];
  const int*   receivers  = (const int*)d_in[4];
  const float* W_up0 = (const float*)d_in[5];
  const float* W_up1 = (const float*)d_in[6];
  const float* W_up2 = (const float*)d_in[7];
  const float* Wm0   = (const float*)d_in[8];
  const float* Wm1   = (const float*)d_in[9];
  const float* Wm2   = (const float*)d_in[10];
  const float* Wd0   = (const float*)d_in[11];
  const float* Wd1   = (const float*)d_in[12];
  const float* Wd2   = (const float*)d_in[13];
  const float* Wsk0  = (const float*)d_in[14];
  const float* Wsk1  = (const float*)d_in[15];
  const float* Wsk2  = (const float*)d_in[16];
  float* out = (float*)d_out;
  float* ws  = (float*)d_ws;

  // ws layout (float units):
  // [cg 2048][mtab NN*144][counts NN][cursor NN][offsets NN+64][edge_sorted NE]
  // [nb 16][Wm1p 2048][Wm2p 5632][mixb][ylm][sedge][msgb]
  float* cgbuf = ws;
  float* mtab  = ws + 2048;
  int* counts      = (int*)(ws + 2048 + (size_t)NN*144);
  int* cursor      = counts + NN;
  int* offsets     = cursor + NN;
  int* edge_sorted = offsets + NN + 64;
  int* nb          = edge_sorted + NE;
  unsigned short* Wm1p = (unsigned short*)(nb + 16);
  unsigned short* Wm2p = Wm1p + 4096;
  unsigned short* mixb = Wm2p + 11264;

  size_t fixed_f = 2048 + (size_t)NN*144 + NN + NN + (NN+64) + NE + 16 + 2048 + 5632;
  size_t ws_f = ws_size/4;
  // per-edge ws: mixb 88f + ylm 4f + sedge 1f + msgb 72f = 165 f
  long long cap_rows = (ws_f > fixed_f) ? (long long)((ws_f - fixed_f)/165) : 0;
  long long capm = cap_rows - 8192;
  if (capm < 16384) capm = 16384;
  int NC = (int)((NE + capm - 1)/capm);
  if (NC < 1) NC = 1;
  if (NC > 15) NC = 15;
  int plane_stride = (int)(NE/NC + 4096);

  unsigned short* ylm  = mixb + (size_t)11*plane_stride*16;
  int* sedge           = (int*)(ylm + (size_t)plane_stride*8);
  unsigned short* msgb = (unsigned short*)(sedge + plane_stride);

  hipMemsetAsync(counts, 0, 2*(size_t)NN*sizeof(int), stream);
  init_kernel<<<71, 256, 0, stream>>>(Wm1, Wm2, cgbuf, Wm1p, Wm2p);
  node_up_kernel<<<(NN*144)/256, 256, 0, stream>>>(node_feats, W_up0, W_up1, W_up2, mtab);
  hist_kernel<<<NE/256, 256, 0, stream>>>(receivers, counts);
  scan_kernel<<<1, 1024, 0, stream>>>(counts, offsets, nb, NC);
  scatter_kernel<<<NE/256, 256, 0, stream>>>(receivers, offsets, cursor, edge_sorted);

  long long chunk_edges_max = NE/NC + 4096;
  int gA  = (int)((chunk_edges_max + 255)/256);
  int gTP = (int)((chunk_edges_max*4 + 255)/256);
  int gSS = (NN*144 + 255)/256;
  for (int ci = 0; ci < NC; ++ci){
    edge_mix_kernel<<<gA, 256, 0, stream>>>(vectors, senders, edge_sorted,
                                            offsets, nb, Wm0, Wm1p, Wm2p,
                                            ci, plane_stride, mixb, ylm, sedge);
    tp_kernel<<<gTP, 256, 0, stream>>>(offsets, nb, mtab, cgbuf, mixb, ylm,
                                       sedge, ci, plane_stride, msgb);
    seg_sum_kernel<<<gSS, 256, 0, stream>>>(offsets, nb, msgb, ci, out);
  }

  node_out_kernel<<<NN*16/256, 256, 0, stream>>>(node_feats, species,
                                                 Wd0, Wd1, Wd2, Wsk0, Wsk1, Wsk2,
                                                 out, out);
}

// Round 10
// 425.754 us; speedup vs baseline: 1.8211x; 1.1089x over previous
//
#include <hip/hip_runtime.h>
#include <math.h>

#define NN 32768
#define NE 524288

typedef __attribute__((ext_vector_type(8))) short short8v;
typedef __attribute__((ext_vector_type(4))) float f32x4;

__device__ __forceinline__ float siluf(float x){
  return x * __builtin_amdgcn_rcpf(1.0f + __expf(-x));
}

__device__ __forceinline__ unsigned short f2bf(float x){
  unsigned int b = __float_as_uint(x);
  unsigned int r = ((b >> 16) & 1u) + 0x7fffu;
  return (unsigned short)((b + r) >> 16);
}

__device__ __forceinline__ unsigned int pk2(float a, float b){
  return (unsigned int)f2bf(a) | ((unsigned int)f2bf(b) << 16);
}

__device__ __forceinline__ float bf2f(unsigned short v){
  return __uint_as_float(((unsigned int)v) << 16);
}

__device__ const int d_PL1[11] = {0,1,2,0,1,1,2,0,1,2,2};
__device__ const int d_PL2[11] = {0,1,2,1,0,2,1,2,1,0,2};
__device__ const int d_PL3[11] = {0,0,0,1,1,1,1,2,2,2,2};

// ---------------------------------------------------------------------------
// CG math (1/PATH_NORM folded). All paths have even l1+l2+l3 -> real part.
// ---------------------------------------------------------------------------
__device__ double factd(int n){ double r=1.0; for(int i=2;i<=n;++i) r*=(double)i; return r; }

__device__ double su2_elem(int l1,int l2,int l3,int m1,int m2){
  int m3=m1+m2;
  if (m3 < -l3 || m3 > l3) return 0.0;
  double pref = sqrt((double)(2*l3+1)*factd(l3+l1-l2)*factd(l3-l1+l2)*factd(l1+l2-l3)/factd(l1+l2+l3+1));
  pref *= sqrt(factd(l3+m3)*factd(l3-m3)*factd(l1-m1)*factd(l1+m1)*factd(l2-m2)*factd(l2+m2));
  double s=0.0;
  for (int k=0;k<=l1+l2-l3;++k){
    int t1=l1+l2-l3-k, t2=l1-m1-k, t3=l2+m2-k, t4=l3-l2+m1+k, t5=l3-l1-m2+k;
    if (t1<0||t2<0||t3<0||t4<0||t5<0) continue;
    double d = factd(k)*factd(t1)*factd(t2)*factd(t3)*factd(t4)*factd(t5);
    s += ((k&1)? -1.0:1.0)/d;
  }
  return pref*s;
}

__device__ void q_elem(int l,int a,int i,double& re,double& im){
  re=0.0; im=0.0;
  const double is2 = 0.7071067811865476;
  int m = a - l;
  if (m==0){ if (i==l) re=1.0; return; }
  if (m>0){
    if (i==l+m)      re = (m&1)? -is2: is2;
    else if (i==l-m) re = is2;
  } else {
    int mm=-m;
    if (i==l-mm)      im = is2;
    else if (i==l+mm) im = (mm&1)? is2 : -is2;
  }
}

// ---------------------------------------------------------------------------
// init kernel: blocks 0..10 = CG table; blocks 11..70 = weight packing.
// ---------------------------------------------------------------------------
__global__ void init_kernel(const float* __restrict__ Wm1,
                            const float* __restrict__ Wm2,
                            float* __restrict__ cgout,
                            unsigned short* __restrict__ Wm1p,
                            unsigned short* __restrict__ Wm2p)
{
  if (blockIdx.x < 11){
    int p = blockIdx.x;
    int t = threadIdx.x;
    if (t >= 125) return;
    int a = t/25, b = (t/5)%5, c = t%5;
    int l1=d_PL1[p], l2=d_PL2[p], l3=d_PL3[p];
    int n1=2*l1+1, n2=2*l2+1, n3=2*l3+1;
    float outv = 0.0f;
    if (a<n1 && b<n2 && c<n3){
      double acc = 0.0;
      for (int i=0;i<n1;++i)
        for (int j=0;j<n2;++j){
          int m1=i-l1, m2=j-l2;
          int m3=m1+m2;
          if (m3 < -l3 || m3 > l3) continue;
          double cv = su2_elem(l1,l2,l3,m1,m2);
          if (cv==0.0) continue;
          int k = m3 + l3;
          double a1r,a1i,a2r,a2i,a3r,a3i;
          q_elem(l1,a,i,a1r,a1i);
          q_elem(l2,b,j,a2r,a2i);
          q_elem(l3,c,k,a3r,a3i);
          double re = (a1r*a2r - a1i*a2i)*a3r + (a1r*a2i + a1i*a2r)*a3i;
          acc += cv*re;
        }
      double invn = (l3==0)? 0.5773502691896258 : 0.5;
      outv = (float)(acc*invn);
    }
    cgout[p*125 + (a*5+b)*5 + c] = outv;
  } else {
    int t = (blockIdx.x - 11)*256 + threadIdx.x;
    if (t < 4096){
      int j = t & 7, lane = (t>>3)&63, ks = (t>>9)&1, ni = t>>10;
      int k = ks*32 + (lane>>4)*8 + j;
      int col = ni*16 + (lane&15);
      Wm1p[t] = f2bf(Wm1[k*64+col]);
    }
    int t2 = t - 4096;
    if (t2 >= 0 && t2 < 11264){
      int j = t2 & 7, lane = (t2>>3)&63, ks = (t2>>9)&1, ni = t2>>10;
      int k = ks*32 + (lane>>4)*8 + j;
      int col = ni*16 + (lane&15);
      Wm2p[t2] = f2bf(Wm2[k*176+col]);
    }
  }
}

// ---------------------------------------------------------------------------
// Node up-projection, iu-major layout (scaled 0.25):
// mtab row: [0:16]=m0 ch; [16:64]=m1 as [iu][16ch]; [64:144]=m2 as [iu][16ch]
// ---------------------------------------------------------------------------
__global__ __launch_bounds__(256) void node_up_kernel(
    const float* __restrict__ nf,
    const float* __restrict__ W0,
    const float* __restrict__ W1,
    const float* __restrict__ W2,
    float* __restrict__ mtab)
{
  int gidx = blockIdx.x*256 + threadIdx.x;
  if (gidx >= NN*144) return;
  int n = gidx/144;
  int col = gidx - n*144;
  const float* f = nf + (size_t)n*144;
  float acc = 0.f;
  if (col < 16){
    int o = col;
    #pragma unroll
    for (int c=0;c<16;++c) acc += f[c]*W0[c*16+o];
  } else if (col < 64){
    int idx = col-16;
    int iu = idx >> 4, o = idx & 15;
    #pragma unroll
    for (int c=0;c<16;++c) acc += f[16+c*3+iu]*W1[c*16+o];
  } else {
    int idx = col-64;
    int iu = idx >> 4, o = idx & 15;
    #pragma unroll
    for (int c=0;c<16;++c) acc += f[64+c*5+iu]*W2[c*16+o];
  }
  mtab[gidx] = 0.25f*acc;
}

// ---------------------------------------------------------------------------
// CSR build
// ---------------------------------------------------------------------------
__global__ __launch_bounds__(256) void hist_kernel(
    const int* __restrict__ recv, int* __restrict__ counts)
{
  int e = blockIdx.x*256 + threadIdx.x;
  if (e < NE) atomicAdd(&counts[recv[e]], 1);
}

__global__ __launch_bounds__(1024) void scan_kernel(
    const int* __restrict__ counts, int* __restrict__ offsets,
    int* __restrict__ nb, int NC)
{
  __shared__ int part[1024];
  int t = threadIdx.x;
  int local[32];
  int s = 0;
  #pragma unroll
  for (int i=0;i<32;++i){ local[i]=counts[t*32+i]; s+=local[i]; }
  part[t]=s;
  __syncthreads();
  for (int off=1; off<1024; off<<=1){
    int v = (t>=off)? part[t-off] : 0;
    __syncthreads();
    part[t] += v;
    __syncthreads();
  }
  int base = part[t] - s;
  int run = base;
  #pragma unroll
  for (int i=0;i<32;++i){ offsets[t*32+i]=run; run+=local[i]; }
  if (t==1023) offsets[NN]=run;

  for (int i=1; i<NC; ++i){
    long long Ti = (long long)NE*i/NC;
    if ((long long)base <= Ti && Ti < (long long)part[t]){
      int run2 = base;
      #pragma unroll
      for (int k=0;k<32;++k){
        int nxt = run2 + local[k];
        if (run2 <= Ti && Ti < nxt) nb[i] = t*32 + k + 1;
        run2 = nxt;
      }
    }
  }
  if (t==0) nb[0]=0;
  if (t==1023) nb[NC]=NN;
}

__global__ __launch_bounds__(256) void scatter_kernel(
    const int* __restrict__ recv, const int* __restrict__ offsets,
    int* __restrict__ cursor, int* __restrict__ edge_sorted)
{
  int e = blockIdx.x*256 + threadIdx.x;
  if (e < NE){
    int r = recv[e];
    int pos = atomicAdd(&cursor[r], 1);
    edge_sorted[offsets[r] + pos] = e;
  }
}

// ---------------------------------------------------------------------------
// Edge MLP + mix with MFMA. Emits mixb planes + per-slot side data
// (ylm bf16 y1/y2, sedge sender id).
// ---------------------------------------------------------------------------
__global__ __launch_bounds__(256) void edge_mix_kernel(
    const float* __restrict__ vectors,
    const int* __restrict__ senders,
    const int* __restrict__ edge_sorted,
    const int* __restrict__ offsets,
    const int* __restrict__ nb,
    const float* __restrict__ Wm0,
    const unsigned short* __restrict__ Wm1p,
    const unsigned short* __restrict__ Wm2p,
    int ci, int plane_stride,
    unsigned short* __restrict__ mixb,
    unsigned short* __restrict__ ylm,
    int* __restrict__ sedge)
{
  __shared__ unsigned short lds_h[4][8*64*8];
  __shared__ float lds_s[4][64];

  int sbase = offsets[nb[ci]];
  int nE = offsets[nb[ci+1]] - sbase;
  int tid = threadIdx.x;
  int wid = tid >> 6;
  int lane = tid & 63;
  int g = lane >> 4;
  int l15 = lane & 15;
  int wb = blockIdx.x*256 + wid*64;
  int slot = wb + lane;

  float vx=0.f, vy=0.f, vz=0.f;
  int snd = 0;
  if (slot < nE){
    int e = edge_sorted[sbase + slot];
    vx = vectors[(size_t)e*3+0];
    vy = vectors[(size_t)e*3+1];
    vz = vectors[(size_t)e*3+2];
    snd = senders[e];
  }
  float r = sqrtf(vx*vx + vy*vy + vz*vz);
  float safe = (r > 1e-9f) ? r : 1.0f;
  float inv_safe = 1.0f/safe;

  const float PIf = 3.14159265358979f;
  float xc = fminf(r*0.25f, 1.0f);
  float s1 = __sinf(PIf*xc);
  float c1 = __cosf(PIf*xc);
  float env = 0.5f*(c1 + 1.0f);
  float pref = 0.70710678118f * env * inv_safe;
  float rb[8];
  {
    float sk=s1, ck=c1;
    rb[0]=pref*sk;
    #pragma unroll
    for (int k=1;k<8;++k){
      float sn = sk*c1 + ck*s1;
      float cn = ck*c1 - sk*s1;
      sk=sn; ck=cn;
      rb[k]=pref*sk;
    }
  }

  if (slot < nE){
    float ux=vx*inv_safe, uy=vy*inv_safe, uz=vz*inv_safe;
    const float SQ3  = 1.73205080757f;
    const float SQ15 = 3.87298334621f;
    union { uint4 u; unsigned short s[8]; } yv;
    yv.s[0]=f2bf(SQ3*uy);  yv.s[1]=f2bf(SQ3*uz);  yv.s[2]=f2bf(SQ3*ux);
    yv.s[3]=f2bf(SQ15*ux*uy);
    yv.s[4]=f2bf(SQ15*uy*uz);
    yv.s[5]=f2bf(1.11803398875f*(3.f*uz*uz-1.f));
    yv.s[6]=f2bf(SQ15*ux*uz);
    yv.s[7]=f2bf(1.93649167310f*(ux*ux-uy*uy));
    *(uint4*)(ylm + (size_t)slot*8) = yv.u;
    sedge[slot] = snd;
  }

  float h[64];
  #pragma unroll
  for (int o=0;o<64;++o) h[o]=0.f;
  #pragma unroll
  for (int i=0;i<8;++i){
    float ri = rb[i];
    #pragma unroll
    for (int o=0;o<64;++o) h[o] += ri*Wm0[i*64+o];
  }

  unsigned short* Lh = lds_h[wid];
  #pragma unroll
  for (int c=0;c<8;++c){
    union { unsigned int u[4]; short8v v; } pk;
    #pragma unroll
    for (int w=0;w<4;++w){
      float a0 = siluf(h[c*8+2*w  ]*0.3535533906f);
      float a1 = siluf(h[c*8+2*w+1]*0.3535533906f);
      pk.u[w] = pk2(a0, a1);
    }
    *(short8v*)(Lh + ((size_t)(c*64 + lane))*8) = pk.v;
  }
  lds_s[wid][lane] = (r == 0.0f) ? 0.0f : 0.125f;

  __syncthreads();

  short8v a[8];
  #pragma unroll
  for (int mi=0;mi<4;++mi){
    #pragma unroll
    for (int ks=0;ks<2;++ks)
      a[mi*2+ks] = *(short8v*)(Lh + ((size_t)((ks*4+g)*64 + mi*16 + l15))*8);
  }
  #pragma unroll 1
  for (int ni=0;ni<4;++ni){
    short8v b0 = *(short8v*)(Wm1p + ((size_t)((ni*2+0)*64 + lane))*8);
    short8v b1 = *(short8v*)(Wm1p + ((size_t)((ni*2+1)*64 + lane))*8);
    int chnk = ni*2 + (l15>>3);
    int cb = l15 & 7;
    #pragma unroll
    for (int mi=0;mi<4;++mi){
      f32x4 acc = {0.f,0.f,0.f,0.f};
      acc = __builtin_amdgcn_mfma_f32_16x16x32_bf16(a[mi*2+0], b0, acc, 0,0,0);
      acc = __builtin_amdgcn_mfma_f32_16x16x32_bf16(a[mi*2+1], b1, acc, 0,0,0);
      #pragma unroll
      for (int reg=0;reg<4;++reg){
        int row = mi*16 + g*4 + reg;
        Lh[((size_t)(chnk*64 + row))*8 + cb] = f2bf(siluf(acc[reg]*0.125f));
      }
    }
  }

  short8v a2[8];
  #pragma unroll
  for (int mi=0;mi<4;++mi){
    #pragma unroll
    for (int ks=0;ks<2;++ks)
      a2[mi*2+ks] = *(short8v*)(Lh + ((size_t)((ks*4+g)*64 + mi*16 + l15))*8);
  }
  f32x4 scv[4];
  #pragma unroll
  for (int mi=0;mi<4;++mi)
    scv[mi] = *(f32x4*)(&lds_s[wid][mi*16 + g*4]);

  #pragma unroll 1
  for (int ni=0;ni<11;++ni){
    short8v b0 = *(short8v*)(Wm2p + ((size_t)((ni*2+0)*64 + lane))*8);
    short8v b1 = *(short8v*)(Wm2p + ((size_t)((ni*2+1)*64 + lane))*8);
    #pragma unroll
    for (int mi=0;mi<4;++mi){
      f32x4 acc = {0.f,0.f,0.f,0.f};
      acc = __builtin_amdgcn_mfma_f32_16x16x32_bf16(a2[mi*2+0], b0, acc, 0,0,0);
      acc = __builtin_amdgcn_mfma_f32_16x16x32_bf16(a2[mi*2+1], b1, acc, 0,0,0);
      #pragma unroll
      for (int reg=0;reg<4;++reg){
        int row = mi*16 + g*4 + reg;
        int sl = wb + row;
        if (sl < nE)
          mixb[((size_t)ni*plane_stride + sl)*16 + l15] = f2bf(acc[reg]*scv[mi][reg]);
      }
    }
  }
}

// ---------------------------------------------------------------------------
// Edge-parallel tensor product, paths grouped by L1 (staged x loads, JIT mix
// loads -> low VGPR). Thread per (slot, channel-quad); writes msgb bf16.
// ---------------------------------------------------------------------------
template<int PIDX,int D1,int L2,int L3>
__device__ __forceinline__ void do_p(
    const float* __restrict__ cgtab, uint2 um,
    const float (&y1)[3], const float (&y2)[5],
    const float (&x)[D1][4],
    float (&msg0)[4], float (&msg1)[4][3], float (&msg2)[4][5])
{
  constexpr int d1=D1, d2=2*L2+1, d3=2*L3+1;
  const float* cgp = cgtab + PIDX*125;

  float yv[d2];
  if constexpr (L2==0){ yv[0]=1.0f; }
  else if constexpr (L2==1){ yv[0]=y1[0]; yv[1]=y1[1]; yv[2]=y1[2]; }
  else {
    #pragma unroll
    for (int j=0;j<5;++j) yv[j]=y2[j];
  }

  float M[d1][d3];
  #pragma unroll
  for (int iu=0;iu<d1;++iu){
    #pragma unroll
    for (int k=0;k<d3;++k){
      float acc = 0.f;
      #pragma unroll
      for (int j=0;j<d2;++j) acc += yv[j]*cgp[(iu*5+j)*5+k];
      M[iu][k]=acc;
    }
  }

  float mx[4];
  mx[0] = __uint_as_float(um.x << 16);
  mx[1] = __uint_as_float(um.x & 0xffff0000u);
  mx[2] = __uint_as_float(um.y << 16);
  mx[3] = __uint_as_float(um.y & 0xffff0000u);

  #pragma unroll
  for (int c=0;c<4;++c){
    #pragma unroll
    for (int k=0;k<d3;++k){
      float t = 0.f;
      #pragma unroll
      for (int iu=0;iu<d1;++iu) t += x[iu][c]*M[iu][k];
      if constexpr (L3==0)      msg0[c]    += mx[c]*t;
      else if constexpr (L3==1) msg1[c][k] += mx[c]*t;
      else                      msg2[c][k] += mx[c]*t;
    }
  }
}

__global__ __launch_bounds__(256) void tp_kernel(
    const int* __restrict__ offsets,
    const int* __restrict__ nb,
    const float* __restrict__ mtab,
    const float* __restrict__ cgtab,
    const unsigned short* __restrict__ mixb,
    const unsigned short* __restrict__ ylm,
    const int* __restrict__ sedge,
    int ci, int plane_stride,
    unsigned short* __restrict__ msgb)
{
  int t = blockIdx.x*256 + threadIdx.x;
  int slot = t >> 2;
  int sbase = offsets[nb[ci]];
  int nE = offsets[nb[ci+1]] - sbase;
  if (slot >= nE) return;
  int c0 = (t & 3)*4;

  union { uint4 u; unsigned short s[8]; } yv;
  yv.u = *(const uint4*)(ylm + (size_t)slot*8);
  int snd = sedge[slot];
  const float* xp = mtab + (size_t)snd*144;

  float y1[3], y2[5];
  y1[0]=bf2f(yv.s[0]); y1[1]=bf2f(yv.s[1]); y1[2]=bf2f(yv.s[2]);
  y2[0]=bf2f(yv.s[3]); y2[1]=bf2f(yv.s[4]); y2[2]=bf2f(yv.s[5]);
  y2[3]=bf2f(yv.s[6]); y2[4]=bf2f(yv.s[7]);

  float msg0[4];
  float msg1[4][3];
  float msg2[4][5];
  #pragma unroll
  for (int c=0;c<4;++c){
    msg0[c]=0.f;
    #pragma unroll
    for (int i=0;i<3;++i) msg1[c][i]=0.f;
    #pragma unroll
    for (int i=0;i<5;++i) msg2[c][i]=0.f;
  }

  #define UM(P) (*(const uint2*)(mixb + ((size_t)(P)*plane_stride + slot)*16 + c0))

  {  // L1 = 0 paths: 0(0,0,0) 3(0,1,1) 7(0,2,2)
    float x0[1][4];
    *(f32x4*)(x0[0]) = *(const f32x4*)(xp + c0);
    do_p< 0,1,0,0>(cgtab,UM(0),y1,y2,x0,msg0,msg1,msg2);
    do_p< 3,1,1,1>(cgtab,UM(3),y1,y2,x0,msg0,msg1,msg2);
    do_p< 7,1,2,2>(cgtab,UM(7),y1,y2,x0,msg0,msg1,msg2);
  }
  {  // L1 = 1 paths: 1(1,1,0) 4(1,0,1) 5(1,2,1) 8(1,1,2)
    float x1[3][4];
    #pragma unroll
    for (int iu=0;iu<3;++iu)
      *(f32x4*)(x1[iu]) = *(const f32x4*)(xp + 16 + iu*16 + c0);
    do_p< 1,3,1,0>(cgtab,UM(1),y1,y2,x1,msg0,msg1,msg2);
    do_p< 4,3,0,1>(cgtab,UM(4),y1,y2,x1,msg0,msg1,msg2);
    do_p< 5,3,2,1>(cgtab,UM(5),y1,y2,x1,msg0,msg1,msg2);
    do_p< 8,3,1,2>(cgtab,UM(8),y1,y2,x1,msg0,msg1,msg2);
  }
  {  // L1 = 2 paths: 2(2,2,0) 6(2,1,1) 9(2,0,2) 10(2,2,2)
    float x2[5][4];
    #pragma unroll
    for (int iu=0;iu<5;++iu)
      *(f32x4*)(x2[iu]) = *(const f32x4*)(xp + 64 + iu*16 + c0);
    do_p< 2,5,2,0>(cgtab,UM(2),y1,y2,x2,msg0,msg1,msg2);
    do_p< 6,5,1,1>(cgtab,UM(6),y1,y2,x2,msg0,msg1,msg2);
    do_p< 9,5,0,2>(cgtab,UM(9),y1,y2,x2,msg0,msg1,msg2);
    do_p<10,5,2,2>(cgtab,UM(10),y1,y2,x2,msg0,msg1,msg2);
  }
  #undef UM

  unsigned short* mr = msgb + (size_t)slot*144;
  {
    uint2 w;
    w.x = pk2(msg0[0], msg0[1]);
    w.y = pk2(msg0[2], msg0[3]);
    *(uint2*)(mr + c0) = w;
  }
  {
    unsigned short* p = mr + 16 + c0*3;
    uint2 w0, w1, w2;
    w0.x = pk2(msg1[0][0], msg1[0][1]);
    w0.y = pk2(msg1[0][2], msg1[1][0]);
    w1.x = pk2(msg1[1][1], msg1[1][2]);
    w1.y = pk2(msg1[2][0], msg1[2][1]);
    w2.x = pk2(msg1[2][2], msg1[3][0]);
    w2.y = pk2(msg1[3][1], msg1[3][2]);
    *(uint2*)(p) = w0;
    *(uint2*)(p+4) = w1;
    *(uint2*)(p+8) = w2;
  }
  {
    unsigned short* p = mr + 64 + c0*5;
    #pragma unroll
    for (int w=0; w<5; ++w){
      int i0 = w*4;
      float v0 = msg2[(i0+0)/5][(i0+0)%5];
      float v1 = msg2[(i0+1)/5][(i0+1)%5];
      float v2 = msg2[(i0+2)/5][(i0+2)%5];
      float v3 = msg2[(i0+3)/5][(i0+3)%5];
      uint2 ww;
      ww.x = pk2(v0, v1);
      ww.y = pk2(v2, v3);
      *(uint2*)(p + i0) = ww;
    }
  }
}

// ---------------------------------------------------------------------------
// Fused segmented-sum + node update. Block = 16 nodes x 16 threads.
// Thread (n,o) sums msgb cols [o*9, o*9+9) into LDS, then node_out math.
// ---------------------------------------------------------------------------
__global__ __launch_bounds__(256) void seg_out_kernel(
    const int* __restrict__ offsets,
    const int* __restrict__ nb,
    const unsigned short* __restrict__ msgb,
    const float* __restrict__ nf,
    const int* __restrict__ species,
    const float* __restrict__ Wd0,
    const float* __restrict__ Wd1,
    const float* __restrict__ Wd2,
    const float* __restrict__ Wsk0,
    const float* __restrict__ Wsk1,
    const float* __restrict__ Wsk2,
    int ci,
    float* __restrict__ out)
{
  __shared__ float accum[16*144];

  int nlo = nb[ci], nhi = nb[ci+1];
  int nblk = blockIdx.x*16;
  if (nblk + 16 <= nlo || nblk >= nhi) return;   // uniform block-level skip

  int tid = threadIdx.x;
  int nloc = tid >> 4;
  int o = tid & 15;
  int n = nblk + nloc;
  bool active = (n >= nlo && n < nhi);

  int cbase = offsets[nlo];
  float acc[9];
  #pragma unroll
  for (int k=0;k<9;++k) acc[k]=0.f;
  if (active){
    int j0 = offsets[n] - cbase;
    int j1 = offsets[n+1] - cbase;
    for (int j=j0; j<j1; ++j){
      const unsigned short* mr = msgb + (size_t)j*144 + o*9;
      #pragma unroll
      for (int k=0;k<9;++k) acc[k] += bf2f(mr[k]);
    }
  }
  #pragma unroll
  for (int k=0;k<9;++k) accum[nloc*144 + o*9 + k] = acc[k];
  __syncthreads();
  if (!active) return;

  const float* an = accum + nloc*144;
  const float* f  = nf + (size_t)n*144;
  int sp = species[n];
  const float* wk0 = Wsk0 + sp*768;
  const float* wk1 = Wsk1 + sp*256;
  const float* wk2 = Wsk2 + sp*256;

  float sa0=0,sa1=0,sa2=0, sf0=0,sf1=0,sf2=0;
  #pragma unroll
  for (int c=0;c<16;++c){
    float aa = an[c], ff = f[c];
    sa0 += aa*Wd0[c*48+o];
    sa1 += aa*Wd0[c*48+16+o];
    sa2 += aa*Wd0[c*48+32+o];
    sf0 += ff*wk0[c*48+o];
    sf1 += ff*wk0[c*48+16+o];
    sf2 += ff*wk0[c*48+32+o];
  }
  float s0 = 0.0625f*sa0 + 0.25f*sf0;
  float s1 = 0.0625f*sa1 + 0.25f*sf1;
  float s2 = 0.0625f*sa2 + 0.25f*sf2;
  float scvv = siluf(s0);
  float g1  = siluf(s1);
  float g2  = siluf(s2);

  float v[3];
  #pragma unroll
  for (int i=0;i<3;++i){
    float av=0, fv=0;
    #pragma unroll
    for (int c=0;c<16;++c){
      av += an[16+c*3+i]*Wd1[c*16+o];
      fv += f[16+c*3+i]*wk1[c*16+o];
    }
    v[i] = (0.0625f*av + 0.25f*fv)*g1;
  }
  float q[5];
  #pragma unroll
  for (int i=0;i<5;++i){
    float av=0, fv=0;
    #pragma unroll
    for (int c=0;c<16;++c){
      av += an[64+c*5+i]*Wd2[c*16+o];
      fv += f[64+c*5+i]*wk2[c*16+o];
    }
    q[i] = (0.0625f*av + 0.25f*fv)*g2;
  }

  float* on = out + (size_t)n*144;
  on[o] = scvv;
  #pragma unroll
  for (int i=0;i<3;++i) on[16+o*3+i] = v[i];
  #pragma unroll
  for (int i=0;i<5;++i) on[64+o*5+i] = q[i];
}

// ---------------------------------------------------------------------------
extern "C" void kernel_launch(void* const* d_in, const int* in_sizes, int n_in,
                              void* d_out, int out_size, void* d_ws, size_t ws_size,
                              hipStream_t stream)
{
  const float* vectors    = (const float*)d_in[0];
  const float* node_feats = (const float*)d_in[1];
  const int*   species    = (const int*)d_in[2];
  const int*   senders    = (const int*)d_in[3];
  const int*   receivers  = (const int*)d_in[4];
  const float* W_up0 = (const float*)d_in[5];
  const float* W_up1 = (const float*)d_in[6];
  const float* W_up2 = (const float*)d_in[7];
  const float* Wm0   = (const float*)d_in[8];
  const float* Wm1   = (const float*)d_in[9];
  const float* Wm2   = (const float*)d_in[10];
  const float* Wd0   = (const float*)d_in[11];
  const float* Wd1   = (const float*)d_in[12];
  const float* Wd2   = (const float*)d_in[13];
  const float* Wsk0  = (const float*)d_in[14];
  const float* Wsk1  = (const float*)d_in[15];
  const float* Wsk2  = (const float*)d_in[16];
  float* out = (float*)d_out;
  float* ws  = (float*)d_ws;

  float* cgbuf = ws;
  float* mtab  = ws + 2048;
  int* counts      = (int*)(ws + 2048 + (size_t)NN*144);
  int* cursor      = counts + NN;
  int* offsets     = cursor + NN;
  int* edge_sorted = offsets + NN + 64;
  int* nb          = edge_sorted + NE;
  unsigned short* Wm1p = (unsigned short*)(nb + 16);
  unsigned short* Wm2p = Wm1p + 4096;
  unsigned short* mixb = Wm2p + 11264;

  size_t fixed_f = 2048 + (size_t)NN*144 + NN + NN + (NN+64) + NE + 16 + 2048 + 5632;
  size_t ws_f = ws_size/4;
  // per-edge ws: mixb 88f + ylm 4f + sedge 1f + msgb 72f = 165 f
  long long cap_rows = (ws_f > fixed_f) ? (long long)((ws_f - fixed_f)/165) : 0;
  long long capm = cap_rows - 8192;
  if (capm < 16384) capm = 16384;
  int NC = (int)((NE + capm - 1)/capm);
  if (NC < 1) NC = 1;
  if (NC > 15) NC = 15;
  int plane_stride = (int)(NE/NC + 4096);

  unsigned short* ylm  = mixb + (size_t)11*plane_stride*16;
  int* sedge           = (int*)(ylm + (size_t)plane_stride*8);
  unsigned short* msgb = (unsigned short*)(sedge + plane_stride);

  hipMemsetAsync(counts, 0, 2*(size_t)NN*sizeof(int), stream);
  init_kernel<<<71, 256, 0, stream>>>(Wm1, Wm2, cgbuf, Wm1p, Wm2p);
  node_up_kernel<<<(NN*144)/256, 256, 0, stream>>>(node_feats, W_up0, W_up1, W_up2, mtab);
  hist_kernel<<<NE/256, 256, 0, stream>>>(receivers, counts);
  scan_kernel<<<1, 1024, 0, stream>>>(counts, offsets, nb, NC);
  scatter_kernel<<<NE/256, 256, 0, stream>>>(receivers, offsets, cursor, edge_sorted);

  long long chunk_edges_max = NE/NC + 4096;
  int gA  = (int)((chunk_edges_max + 255)/256);
  int gTP = (int)((chunk_edges_max*4 + 255)/256);
  int gSO = (NN + 15)/16;
  for (int ci = 0; ci < NC; ++ci){
    edge_mix_kernel<<<gA, 256, 0, stream>>>(vectors, senders, edge_sorted,
                                            offsets, nb, Wm0, Wm1p, Wm2p,
                                            ci, plane_stride, mixb, ylm, sedge);
    tp_kernel<<<gTP, 256, 0, stream>>>(offsets, nb, mtab, cgbuf, mixb, ylm,
                                       sedge, ci, plane_stride, msgb);
    seg_out_kernel<<<gSO, 256, 0, stream>>>(offsets, nb, msgb, node_feats,
                                            species, Wd0, Wd1, Wd2,
                                            Wsk0, Wsk1, Wsk2, ci, out);
  }
}

// Round 11
// 404.752 us; speedup vs baseline: 1.9156x; 1.0519x over previous
//
#include <hip/hip_runtime.h>
#include <math.h>

#define NN 32768
#define NE 524288

typedef __attribute__((ext_vector_type(8))) short short8v;
typedef __attribute__((ext_vector_type(4))) float f32x4;

__device__ __forceinline__ float siluf(float x){
  return x * __builtin_amdgcn_rcpf(1.0f + __expf(-x));
}

__device__ __forceinline__ unsigned short f2bf(float x){
  unsigned int b = __float_as_uint(x);
  unsigned int r = ((b >> 16) & 1u) + 0x7fffu;
  return (unsigned short)((b + r) >> 16);
}

__device__ __forceinline__ unsigned int pk2(float a, float b){
  return (unsigned int)f2bf(a) | ((unsigned int)f2bf(b) << 16);
}

__device__ __forceinline__ float bf2f(unsigned short v){
  return __uint_as_float(((unsigned int)v) << 16);
}

__device__ __forceinline__ void unp4(uint2 u, float* x){
  x[0] = __uint_as_float(u.x << 16);
  x[1] = __uint_as_float(u.x & 0xffff0000u);
  x[2] = __uint_as_float(u.y << 16);
  x[3] = __uint_as_float(u.y & 0xffff0000u);
}

__device__ const int d_PL1[11] = {0,1,2,0,1,1,2,0,1,2,2};
__device__ const int d_PL2[11] = {0,1,2,1,0,2,1,2,1,0,2};
__device__ const int d_PL3[11] = {0,0,0,1,1,1,1,2,2,2,2};

// ---------------------------------------------------------------------------
// CG math (1/PATH_NORM folded). All paths have even l1+l2+l3 -> real part.
// ---------------------------------------------------------------------------
__device__ double factd(int n){ double r=1.0; for(int i=2;i<=n;++i) r*=(double)i; return r; }

__device__ double su2_elem(int l1,int l2,int l3,int m1,int m2){
  int m3=m1+m2;
  if (m3 < -l3 || m3 > l3) return 0.0;
  double pref = sqrt((double)(2*l3+1)*factd(l3+l1-l2)*factd(l3-l1+l2)*factd(l1+l2-l3)/factd(l1+l2+l3+1));
  pref *= sqrt(factd(l3+m3)*factd(l3-m3)*factd(l1-m1)*factd(l1+m1)*factd(l2-m2)*factd(l2+m2));
  double s=0.0;
  for (int k=0;k<=l1+l2-l3;++k){
    int t1=l1+l2-l3-k, t2=l1-m1-k, t3=l2+m2-k, t4=l3-l2+m1+k, t5=l3-l1-m2+k;
    if (t1<0||t2<0||t3<0||t4<0||t5<0) continue;
    double d = factd(k)*factd(t1)*factd(t2)*factd(t3)*factd(t4)*factd(t5);
    s += ((k&1)? -1.0:1.0)/d;
  }
  return pref*s;
}

__device__ void q_elem(int l,int a,int i,double& re,double& im){
  re=0.0; im=0.0;
  const double is2 = 0.7071067811865476;
  int m = a - l;
  if (m==0){ if (i==l) re=1.0; return; }
  if (m>0){
    if (i==l+m)      re = (m&1)? -is2: is2;
    else if (i==l-m) re = is2;
  } else {
    int mm=-m;
    if (i==l-mm)      im = is2;
    else if (i==l+mm) im = (mm&1)? is2 : -is2;
  }
}

// ---------------------------------------------------------------------------
// init kernel: blocks 0..10 = CG table; blocks 11..70 = weight packing.
// ---------------------------------------------------------------------------
__global__ void init_kernel(const float* __restrict__ Wm1,
                            const float* __restrict__ Wm2,
                            float* __restrict__ cgout,
                            unsigned short* __restrict__ Wm1p,
                            unsigned short* __restrict__ Wm2p)
{
  if (blockIdx.x < 11){
    int p = blockIdx.x;
    int t = threadIdx.x;
    if (t >= 125) return;
    int a = t/25, b = (t/5)%5, c = t%5;
    int l1=d_PL1[p], l2=d_PL2[p], l3=d_PL3[p];
    int n1=2*l1+1, n2=2*l2+1, n3=2*l3+1;
    float outv = 0.0f;
    if (a<n1 && b<n2 && c<n3){
      double acc = 0.0;
      for (int i=0;i<n1;++i)
        for (int j=0;j<n2;++j){
          int m1=i-l1, m2=j-l2;
          int m3=m1+m2;
          if (m3 < -l3 || m3 > l3) continue;
          double cv = su2_elem(l1,l2,l3,m1,m2);
          if (cv==0.0) continue;
          int k = m3 + l3;
          double a1r,a1i,a2r,a2i,a3r,a3i;
          q_elem(l1,a,i,a1r,a1i);
          q_elem(l2,b,j,a2r,a2i);
          q_elem(l3,c,k,a3r,a3i);
          double re = (a1r*a2r - a1i*a2i)*a3r + (a1r*a2i + a1i*a2r)*a3i;
          acc += cv*re;
        }
      double invn = (l3==0)? 0.5773502691896258 : 0.5;
      outv = (float)(acc*invn);
    }
    cgout[p*125 + (a*5+b)*5 + c] = outv;
  } else {
    int t = (blockIdx.x - 11)*256 + threadIdx.x;
    if (t < 4096){
      int j = t & 7, lane = (t>>3)&63, ks = (t>>9)&1, ni = t>>10;
      int k = ks*32 + (lane>>4)*8 + j;
      int col = ni*16 + (lane&15);
      Wm1p[t] = f2bf(Wm1[k*64+col]);
    }
    int t2 = t - 4096;
    if (t2 >= 0 && t2 < 11264){
      int j = t2 & 7, lane = (t2>>3)&63, ks = (t2>>9)&1, ni = t2>>10;
      int k = ks*32 + (lane>>4)*8 + j;
      int col = ni*16 + (lane&15);
      Wm2p[t2] = f2bf(Wm2[k*176+col]);
    }
  }
}

// ---------------------------------------------------------------------------
// Node up-projection -> bf16, iu-major layout (scaled 0.25):
// row: [0:16]=m0 ch; [16:64]=m1 as [iu][16ch]; [64:144]=m2 as [iu][16ch]
// ---------------------------------------------------------------------------
__global__ __launch_bounds__(256) void node_up_kernel(
    const float* __restrict__ nf,
    const float* __restrict__ W0,
    const float* __restrict__ W1,
    const float* __restrict__ W2,
    unsigned short* __restrict__ mtabh)
{
  int gidx = blockIdx.x*256 + threadIdx.x;
  if (gidx >= NN*144) return;
  int n = gidx/144;
  int col = gidx - n*144;
  const float* f = nf + (size_t)n*144;
  float acc = 0.f;
  if (col < 16){
    int o = col;
    #pragma unroll
    for (int c=0;c<16;++c) acc += f[c]*W0[c*16+o];
  } else if (col < 64){
    int idx = col-16;
    int iu = idx >> 4, o = idx & 15;
    #pragma unroll
    for (int c=0;c<16;++c) acc += f[16+c*3+iu]*W1[c*16+o];
  } else {
    int idx = col-64;
    int iu = idx >> 4, o = idx & 15;
    #pragma unroll
    for (int c=0;c<16;++c) acc += f[64+c*5+iu]*W2[c*16+o];
  }
  mtabh[gidx] = f2bf(0.25f*acc);
}

// ---------------------------------------------------------------------------
// CSR build
// ---------------------------------------------------------------------------
__global__ __launch_bounds__(256) void hist_kernel(
    const int* __restrict__ recv, int* __restrict__ counts)
{
  int e = blockIdx.x*256 + threadIdx.x;
  if (e < NE) atomicAdd(&counts[recv[e]], 1);
}

__global__ __launch_bounds__(1024) void scan_kernel(
    const int* __restrict__ counts, int* __restrict__ offsets,
    int* __restrict__ nb, int NC)
{
  __shared__ int part[1024];
  int t = threadIdx.x;
  int local[32];
  int s = 0;
  #pragma unroll
  for (int i=0;i<32;++i){ local[i]=counts[t*32+i]; s+=local[i]; }
  part[t]=s;
  __syncthreads();
  for (int off=1; off<1024; off<<=1){
    int v = (t>=off)? part[t-off] : 0;
    __syncthreads();
    part[t] += v;
    __syncthreads();
  }
  int base = part[t] - s;
  int run = base;
  #pragma unroll
  for (int i=0;i<32;++i){ offsets[t*32+i]=run; run+=local[i]; }
  if (t==1023) offsets[NN]=run;

  for (int i=1; i<NC; ++i){
    long long Ti = (long long)NE*i/NC;
    if ((long long)base <= Ti && Ti < (long long)part[t]){
      int run2 = base;
      #pragma unroll
      for (int k=0;k<32;++k){
        int nxt = run2 + local[k];
        if (run2 <= Ti && Ti < nxt) nb[i] = t*32 + k + 1;
        run2 = nxt;
      }
    }
  }
  if (t==0) nb[0]=0;
  if (t==1023) nb[NC]=NN;
}

__global__ __launch_bounds__(256) void scatter_kernel(
    const int* __restrict__ recv, const int* __restrict__ offsets,
    int* __restrict__ cursor, int* __restrict__ edge_sorted)
{
  int e = blockIdx.x*256 + threadIdx.x;
  if (e < NE){
    int r = recv[e];
    int pos = atomicAdd(&cursor[r], 1);
    edge_sorted[offsets[r] + pos] = e;
  }
}

// ---------------------------------------------------------------------------
// Edge MLP + mix with MFMA. Emits mixb planes + per-slot side data
// (ylm bf16 y1/y2, sedge sender id).
// ---------------------------------------------------------------------------
__global__ __launch_bounds__(256) void edge_mix_kernel(
    const float* __restrict__ vectors,
    const int* __restrict__ senders,
    const int* __restrict__ edge_sorted,
    const int* __restrict__ offsets,
    const int* __restrict__ nb,
    const float* __restrict__ Wm0,
    const unsigned short* __restrict__ Wm1p,
    const unsigned short* __restrict__ Wm2p,
    int ci, int plane_stride,
    unsigned short* __restrict__ mixb,
    unsigned short* __restrict__ ylm,
    int* __restrict__ sedge)
{
  __shared__ unsigned short lds_h[4][8*64*8];
  __shared__ float lds_s[4][64];

  int sbase = offsets[nb[ci]];
  int nE = offsets[nb[ci+1]] - sbase;
  int tid = threadIdx.x;
  int wid = tid >> 6;
  int lane = tid & 63;
  int g = lane >> 4;
  int l15 = lane & 15;
  int wb = blockIdx.x*256 + wid*64;
  int slot = wb + lane;

  float vx=0.f, vy=0.f, vz=0.f;
  int snd = 0;
  if (slot < nE){
    int e = edge_sorted[sbase + slot];
    vx = vectors[(size_t)e*3+0];
    vy = vectors[(size_t)e*3+1];
    vz = vectors[(size_t)e*3+2];
    snd = senders[e];
  }
  float r = sqrtf(vx*vx + vy*vy + vz*vz);
  float safe = (r > 1e-9f) ? r : 1.0f;
  float inv_safe = 1.0f/safe;

  const float PIf = 3.14159265358979f;
  float xc = fminf(r*0.25f, 1.0f);
  float s1 = __sinf(PIf*xc);
  float c1 = __cosf(PIf*xc);
  float env = 0.5f*(c1 + 1.0f);
  float pref = 0.70710678118f * env * inv_safe;
  float rb[8];
  {
    float sk=s1, ck=c1;
    rb[0]=pref*sk;
    #pragma unroll
    for (int k=1;k<8;++k){
      float sn = sk*c1 + ck*s1;
      float cn = ck*c1 - sk*s1;
      sk=sn; ck=cn;
      rb[k]=pref*sk;
    }
  }

  if (slot < nE){
    float ux=vx*inv_safe, uy=vy*inv_safe, uz=vz*inv_safe;
    const float SQ3  = 1.73205080757f;
    const float SQ15 = 3.87298334621f;
    union { uint4 u; unsigned short s[8]; } yv;
    yv.s[0]=f2bf(SQ3*uy);  yv.s[1]=f2bf(SQ3*uz);  yv.s[2]=f2bf(SQ3*ux);
    yv.s[3]=f2bf(SQ15*ux*uy);
    yv.s[4]=f2bf(SQ15*uy*uz);
    yv.s[5]=f2bf(1.11803398875f*(3.f*uz*uz-1.f));
    yv.s[6]=f2bf(SQ15*ux*uz);
    yv.s[7]=f2bf(1.93649167310f*(ux*ux-uy*uy));
    *(uint4*)(ylm + (size_t)slot*8) = yv.u;
    sedge[slot] = snd;
  }

  float h[64];
  #pragma unroll
  for (int o=0;o<64;++o) h[o]=0.f;
  #pragma unroll
  for (int i=0;i<8;++i){
    float ri = rb[i];
    #pragma unroll
    for (int o=0;o<64;++o) h[o] += ri*Wm0[i*64+o];
  }

  unsigned short* Lh = lds_h[wid];
  #pragma unroll
  for (int c=0;c<8;++c){
    union { unsigned int u[4]; short8v v; } pk;
    #pragma unroll
    for (int w=0;w<4;++w){
      float a0 = siluf(h[c*8+2*w  ]*0.3535533906f);
      float a1 = siluf(h[c*8+2*w+1]*0.3535533906f);
      pk.u[w] = pk2(a0, a1);
    }
    *(short8v*)(Lh + ((size_t)(c*64 + lane))*8) = pk.v;
  }
  lds_s[wid][lane] = (r == 0.0f) ? 0.0f : 0.125f;

  __syncthreads();

  short8v a[8];
  #pragma unroll
  for (int mi=0;mi<4;++mi){
    #pragma unroll
    for (int ks=0;ks<2;++ks)
      a[mi*2+ks] = *(short8v*)(Lh + ((size_t)((ks*4+g)*64 + mi*16 + l15))*8);
  }
  #pragma unroll 1
  for (int ni=0;ni<4;++ni){
    short8v b0 = *(short8v*)(Wm1p + ((size_t)((ni*2+0)*64 + lane))*8);
    short8v b1 = *(short8v*)(Wm1p + ((size_t)((ni*2+1)*64 + lane))*8);
    int chnk = ni*2 + (l15>>3);
    int cb = l15 & 7;
    #pragma unroll
    for (int mi=0;mi<4;++mi){
      f32x4 acc = {0.f,0.f,0.f,0.f};
      acc = __builtin_amdgcn_mfma_f32_16x16x32_bf16(a[mi*2+0], b0, acc, 0,0,0);
      acc = __builtin_amdgcn_mfma_f32_16x16x32_bf16(a[mi*2+1], b1, acc, 0,0,0);
      #pragma unroll
      for (int reg=0;reg<4;++reg){
        int row = mi*16 + g*4 + reg;
        Lh[((size_t)(chnk*64 + row))*8 + cb] = f2bf(siluf(acc[reg]*0.125f));
      }
    }
  }

  short8v a2[8];
  #pragma unroll
  for (int mi=0;mi<4;++mi){
    #pragma unroll
    for (int ks=0;ks<2;++ks)
      a2[mi*2+ks] = *(short8v*)(Lh + ((size_t)((ks*4+g)*64 + mi*16 + l15))*8);
  }
  f32x4 scv[4];
  #pragma unroll
  for (int mi=0;mi<4;++mi)
    scv[mi] = *(f32x4*)(&lds_s[wid][mi*16 + g*4]);

  #pragma unroll 1
  for (int ni=0;ni<11;++ni){
    short8v b0 = *(short8v*)(Wm2p + ((size_t)((ni*2+0)*64 + lane))*8);
    short8v b1 = *(short8v*)(Wm2p + ((size_t)((ni*2+1)*64 + lane))*8);
    #pragma unroll
    for (int mi=0;mi<4;++mi){
      f32x4 acc = {0.f,0.f,0.f,0.f};
      acc = __builtin_amdgcn_mfma_f32_16x16x32_bf16(a2[mi*2+0], b0, acc, 0,0,0);
      acc = __builtin_amdgcn_mfma_f32_16x16x32_bf16(a2[mi*2+1], b1, acc, 0,0,0);
      #pragma unroll
      for (int reg=0;reg<4;++reg){
        int row = mi*16 + g*4 + reg;
        int sl = wb + row;
        if (sl < nE)
          mixb[((size_t)ni*plane_stride + sl)*16 + l15] = f2bf(acc[reg]*scv[mi][reg]);
      }
    }
  }
}

// ---------------------------------------------------------------------------
// Edge-parallel tensor product. x loads = 9 packed uint2 (bf16), unpacked
// per path-group; JIT mix loads. Thread per (slot, channel-quad).
// ---------------------------------------------------------------------------
template<int PIDX,int D1,int L2,int L3>
__device__ __forceinline__ void do_p(
    const float* __restrict__ cgtab, uint2 um,
    const float (&y1)[3], const float (&y2)[5],
    const float (&x)[D1][4],
    float (&msg0)[4], float (&msg1)[4][3], float (&msg2)[4][5])
{
  constexpr int d1=D1, d2=2*L2+1, d3=2*L3+1;
  const float* cgp = cgtab + PIDX*125;

  float yv[d2];
  if constexpr (L2==0){ yv[0]=1.0f; }
  else if constexpr (L2==1){ yv[0]=y1[0]; yv[1]=y1[1]; yv[2]=y1[2]; }
  else {
    #pragma unroll
    for (int j=0;j<5;++j) yv[j]=y2[j];
  }

  float M[d1][d3];
  #pragma unroll
  for (int iu=0;iu<d1;++iu){
    #pragma unroll
    for (int k=0;k<d3;++k){
      float acc = 0.f;
      #pragma unroll
      for (int j=0;j<d2;++j) acc += yv[j]*cgp[(iu*5+j)*5+k];
      M[iu][k]=acc;
    }
  }

  float mx[4];
  mx[0] = __uint_as_float(um.x << 16);
  mx[1] = __uint_as_float(um.x & 0xffff0000u);
  mx[2] = __uint_as_float(um.y << 16);
  mx[3] = __uint_as_float(um.y & 0xffff0000u);

  #pragma unroll
  for (int c=0;c<4;++c){
    #pragma unroll
    for (int k=0;k<d3;++k){
      float t = 0.f;
      #pragma unroll
      for (int iu=0;iu<d1;++iu) t += x[iu][c]*M[iu][k];
      if constexpr (L3==0)      msg0[c]    += mx[c]*t;
      else if constexpr (L3==1) msg1[c][k] += mx[c]*t;
      else                      msg2[c][k] += mx[c]*t;
    }
  }
}

__global__ __launch_bounds__(256) void tp_kernel(
    const int* __restrict__ offsets,
    const int* __restrict__ nb,
    const unsigned short* __restrict__ mtabh,
    const float* __restrict__ cgtab,
    const unsigned short* __restrict__ mixb,
    const unsigned short* __restrict__ ylm,
    const int* __restrict__ sedge,
    int ci, int plane_stride,
    unsigned short* __restrict__ msgb)
{
  int t = blockIdx.x*256 + threadIdx.x;
  int slot = t >> 2;
  int sbase = offsets[nb[ci]];
  int nE = offsets[nb[ci+1]] - sbase;
  if (slot >= nE) return;
  int c0 = (t & 3)*4;

  union { uint4 u; unsigned short s[8]; } yv;
  yv.u = *(const uint4*)(ylm + (size_t)slot*8);
  int snd = sedge[slot];
  const unsigned short* xp = mtabh + (size_t)snd*144;

  // packed x loads, issued upfront (18 VGPR total)
  uint2 px0 = *(const uint2*)(xp + c0);
  uint2 px1[3];
  #pragma unroll
  for (int iu=0;iu<3;++iu) px1[iu] = *(const uint2*)(xp + 16 + iu*16 + c0);
  uint2 px2[5];
  #pragma unroll
  for (int iu=0;iu<5;++iu) px2[iu] = *(const uint2*)(xp + 64 + iu*16 + c0);

  float y1[3], y2[5];
  y1[0]=bf2f(yv.s[0]); y1[1]=bf2f(yv.s[1]); y1[2]=bf2f(yv.s[2]);
  y2[0]=bf2f(yv.s[3]); y2[1]=bf2f(yv.s[4]); y2[2]=bf2f(yv.s[5]);
  y2[3]=bf2f(yv.s[6]); y2[4]=bf2f(yv.s[7]);

  float msg0[4];
  float msg1[4][3];
  float msg2[4][5];
  #pragma unroll
  for (int c=0;c<4;++c){
    msg0[c]=0.f;
    #pragma unroll
    for (int i=0;i<3;++i) msg1[c][i]=0.f;
    #pragma unroll
    for (int i=0;i<5;++i) msg2[c][i]=0.f;
  }

  #define UM(P) (*(const uint2*)(mixb + ((size_t)(P)*plane_stride + slot)*16 + c0))

  {  // L1 = 0 paths: 0(0,0,0) 3(0,1,1) 7(0,2,2)
    float x0[1][4];
    unp4(px0, x0[0]);
    do_p< 0,1,0,0>(cgtab,UM(0),y1,y2,x0,msg0,msg1,msg2);
    do_p< 3,1,1,1>(cgtab,UM(3),y1,y2,x0,msg0,msg1,msg2);
    do_p< 7,1,2,2>(cgtab,UM(7),y1,y2,x0,msg0,msg1,msg2);
  }
  {  // L1 = 1 paths: 1(1,1,0) 4(1,0,1) 5(1,2,1) 8(1,1,2)
    float x1[3][4];
    #pragma unroll
    for (int iu=0;iu<3;++iu) unp4(px1[iu], x1[iu]);
    do_p< 1,3,1,0>(cgtab,UM(1),y1,y2,x1,msg0,msg1,msg2);
    do_p< 4,3,0,1>(cgtab,UM(4),y1,y2,x1,msg0,msg1,msg2);
    do_p< 5,3,2,1>(cgtab,UM(5),y1,y2,x1,msg0,msg1,msg2);
    do_p< 8,3,1,2>(cgtab,UM(8),y1,y2,x1,msg0,msg1,msg2);
  }
  {  // L1 = 2 paths: 2(2,2,0) 6(2,1,1) 9(2,0,2) 10(2,2,2)
    float x2[5][4];
    #pragma unroll
    for (int iu=0;iu<5;++iu) unp4(px2[iu], x2[iu]);
    do_p< 2,5,2,0>(cgtab,UM(2),y1,y2,x2,msg0,msg1,msg2);
    do_p< 6,5,1,1>(cgtab,UM(6),y1,y2,x2,msg0,msg1,msg2);
    do_p< 9,5,0,2>(cgtab,UM(9),y1,y2,x2,msg0,msg1,msg2);
    do_p<10,5,2,2>(cgtab,UM(10),y1,y2,x2,msg0,msg1,msg2);
  }
  #undef UM

  unsigned short* mr = msgb + (size_t)slot*144;
  {
    uint2 w;
    w.x = pk2(msg0[0], msg0[1]);
    w.y = pk2(msg0[2], msg0[3]);
    *(uint2*)(mr + c0) = w;
  }
  {
    unsigned short* p = mr + 16 + c0*3;
    uint2 w0, w1, w2;
    w0.x = pk2(msg1[0][0], msg1[0][1]);
    w0.y = pk2(msg1[0][2], msg1[1][0]);
    w1.x = pk2(msg1[1][1], msg1[1][2]);
    w1.y = pk2(msg1[2][0], msg1[2][1]);
    w2.x = pk2(msg1[2][2], msg1[3][0]);
    w2.y = pk2(msg1[3][1], msg1[3][2]);
    *(uint2*)(p) = w0;
    *(uint2*)(p+4) = w1;
    *(uint2*)(p+8) = w2;
  }
  {
    unsigned short* p = mr + 64 + c0*5;
    #pragma unroll
    for (int w=0; w<5; ++w){
      int i0 = w*4;
      float v0 = msg2[(i0+0)/5][(i0+0)%5];
      float v1 = msg2[(i0+1)/5][(i0+1)%5];
      float v2 = msg2[(i0+2)/5][(i0+2)%5];
      float v3 = msg2[(i0+3)/5][(i0+3)%5];
      uint2 ww;
      ww.x = pk2(v0, v1);
      ww.y = pk2(v2, v3);
      *(uint2*)(p + i0) = ww;
    }
  }
}

// ---------------------------------------------------------------------------
// Fused segmented-sum + node update. Block = 16 nodes x 16 threads.
// ---------------------------------------------------------------------------
__global__ __launch_bounds__(256) void seg_out_kernel(
    const int* __restrict__ offsets,
    const int* __restrict__ nb,
    const unsigned short* __restrict__ msgb,
    const float* __restrict__ nf,
    const int* __restrict__ species,
    const float* __restrict__ Wd0,
    const float* __restrict__ Wd1,
    const float* __restrict__ Wd2,
    const float* __restrict__ Wsk0,
    const float* __restrict__ Wsk1,
    const float* __restrict__ Wsk2,
    int ci,
    float* __restrict__ out)
{
  __shared__ float accum[16*144];

  int nlo = nb[ci], nhi = nb[ci+1];
  int nblk = blockIdx.x*16;
  if (nblk + 16 <= nlo || nblk >= nhi) return;

  int tid = threadIdx.x;
  int nloc = tid >> 4;
  int o = tid & 15;
  int n = nblk + nloc;
  bool active = (n >= nlo && n < nhi);

  int cbase = offsets[nlo];
  float acc[9];
  #pragma unroll
  for (int k=0;k<9;++k) acc[k]=0.f;
  if (active){
    int j0 = offsets[n] - cbase;
    int j1 = offsets[n+1] - cbase;
    for (int j=j0; j<j1; ++j){
      const unsigned short* mr = msgb + (size_t)j*144 + o*9;
      #pragma unroll
      for (int k=0;k<9;++k) acc[k] += bf2f(mr[k]);
    }
  }
  #pragma unroll
  for (int k=0;k<9;++k) accum[nloc*144 + o*9 + k] = acc[k];
  __syncthreads();
  if (!active) return;

  const float* an = accum + nloc*144;
  const float* f  = nf + (size_t)n*144;
  int sp = species[n];
  const float* wk0 = Wsk0 + sp*768;
  const float* wk1 = Wsk1 + sp*256;
  const float* wk2 = Wsk2 + sp*256;

  float sa0=0,sa1=0,sa2=0, sf0=0,sf1=0,sf2=0;
  #pragma unroll
  for (int c=0;c<16;++c){
    float aa = an[c], ff = f[c];
    sa0 += aa*Wd0[c*48+o];
    sa1 += aa*Wd0[c*48+16+o];
    sa2 += aa*Wd0[c*48+32+o];
    sf0 += ff*wk0[c*48+o];
    sf1 += ff*wk0[c*48+16+o];
    sf2 += ff*wk0[c*48+32+o];
  }
  float s0 = 0.0625f*sa0 + 0.25f*sf0;
  float s1 = 0.0625f*sa1 + 0.25f*sf1;
  float s2 = 0.0625f*sa2 + 0.25f*sf2;
  float scvv = siluf(s0);
  float g1  = siluf(s1);
  float g2  = siluf(s2);

  float v[3];
  #pragma unroll
  for (int i=0;i<3;++i){
    float av=0, fv=0;
    #pragma unroll
    for (int c=0;c<16;++c){
      av += an[16+c*3+i]*Wd1[c*16+o];
      fv += f[16+c*3+i]*wk1[c*16+o];
    }
    v[i] = (0.0625f*av + 0.25f*fv)*g1;
  }
  float q[5];
  #pragma unroll
  for (int i=0;i<5;++i){
    float av=0, fv=0;
    #pragma unroll
    for (int c=0;c<16;++c){
      av += an[64+c*5+i]*Wd2[c*16+o];
      fv += f[64+c*5+i]*wk2[c*16+o];
    }
    q[i] = (0.0625f*av + 0.25f*fv)*g2;
  }

  float* on = out + (size_t)n*144;
  on[o] = scvv;
  #pragma unroll
  for (int i=0;i<3;++i) on[16+o*3+i] = v[i];
  #pragma unroll
  for (int i=0;i<5;++i) on[64+o*5+i] = q[i];
}

// ---------------------------------------------------------------------------
extern "C" void kernel_launch(void* const* d_in, const int* in_sizes, int n_in,
                              void* d_out, int out_size, void* d_ws, size_t ws_size,
                              hipStream_t stream)
{
  const float* vectors    = (const float*)d_in[0];
  const float* node_feats = (const float*)d_in[1];
  const int*   species    = (const int*)d_in[2];
  const int*   senders    = (const int*)d_in[3];
  const int*   receivers  = (const int*)d_in[4];
  const float* W_up0 = (const float*)d_in[5];
  const float* W_up1 = (const float*)d_in[6];
  const float* W_up2 = (const float*)d_in[7];
  const float* Wm0   = (const float*)d_in[8];
  const float* Wm1   = (const float*)d_in[9];
  const float* Wm2   = (const float*)d_in[10];
  const float* Wd0   = (const float*)d_in[11];
  const float* Wd1   = (const float*)d_in[12];
  const float* Wd2   = (const float*)d_in[13];
  const float* Wsk0  = (const float*)d_in[14];
  const float* Wsk1  = (const float*)d_in[15];
  const float* Wsk2  = (const float*)d_in[16];
  float* out = (float*)d_out;
  float* ws  = (float*)d_ws;

  // ws layout (float units):
  // [cg 2048][mtabh bf16 NN*144 = NN*72 f][counts NN][cursor NN][offsets NN+64]
  // [edge_sorted NE][nb 16][Wm1p 2048][Wm2p 5632][mixb][ylm][sedge][msgb]
  float* cgbuf = ws;
  unsigned short* mtabh = (unsigned short*)(ws + 2048);
  int* counts      = (int*)(ws + 2048 + (size_t)NN*72);
  int* cursor      = counts + NN;
  int* offsets     = cursor + NN;
  int* edge_sorted = offsets + NN + 64;
  int* nb          = edge_sorted + NE;
  unsigned short* Wm1p = (unsigned short*)(nb + 16);
  unsigned short* Wm2p = Wm1p + 4096;
  unsigned short* mixb = Wm2p + 11264;

  size_t fixed_f = 2048 + (size_t)NN*72 + NN + NN + (NN+64) + NE + 16 + 2048 + 5632;
  size_t ws_f = ws_size/4;
  // per-edge ws: mixb 88f + ylm 4f + sedge 1f + msgb 72f = 165 f
  long long cap_rows = (ws_f > fixed_f) ? (long long)((ws_f - fixed_f)/165) : 0;
  long long capm = cap_rows - 8192;
  if (capm < 16384) capm = 16384;
  int NC = (int)((NE + capm - 1)/capm);
  if (NC < 1) NC = 1;
  if (NC > 15) NC = 15;
  int plane_stride = (int)(NE/NC + 4096);

  unsigned short* ylm  = mixb + (size_t)11*plane_stride*16;
  int* sedge           = (int*)(ylm + (size_t)plane_stride*8);
  unsigned short* msgb = (unsigned short*)(sedge + plane_stride);

  hipMemsetAsync(counts, 0, 2*(size_t)NN*sizeof(int), stream);
  init_kernel<<<71, 256, 0, stream>>>(Wm1, Wm2, cgbuf, Wm1p, Wm2p);
  node_up_kernel<<<(NN*144)/256, 256, 0, stream>>>(node_feats, W_up0, W_up1, W_up2, mtabh);
  hist_kernel<<<NE/256, 256, 0, stream>>>(receivers, counts);
  scan_kernel<<<1, 1024, 0, stream>>>(counts, offsets, nb, NC);
  scatter_kernel<<<NE/256, 256, 0, stream>>>(receivers, offsets, cursor, edge_sorted);

  long long chunk_edges_max = NE/NC + 4096;
  int gA  = (int)((chunk_edges_max + 255)/256);
  int gTP = (int)((chunk_edges_max*4 + 255)/256);
  int gSO = (NN + 15)/16;
  for (int ci = 0; ci < NC; ++ci){
    edge_mix_kernel<<<gA, 256, 0, stream>>>(vectors, senders, edge_sorted,
                                            offsets, nb, Wm0, Wm1p, Wm2p,
                                            ci, plane_stride, mixb, ylm, sedge);
    tp_kernel<<<gTP, 256, 0, stream>>>(offsets, nb, mtabh, cgbuf, mixb, ylm,
                                       sedge, ci, plane_stride, msgb);
    seg_out_kernel<<<gSO, 256, 0, stream>>>(offsets, nb, msgb, node_feats,
                                            species, Wd0, Wd1, Wd2,
                                            Wsk0, Wsk1, Wsk2, ci, out);
  }
}

// Round 12
// 363.072 us; speedup vs baseline: 2.1356x; 1.1148x over previous
//
#include <hip/hip_runtime.h>
#include <math.h>

#define NN 32768
#define NE 524288

typedef __attribute__((ext_vector_type(8))) short short8v;
typedef __attribute__((ext_vector_type(4))) float f32x4;

__device__ __forceinline__ float siluf(float x){
  return x * __builtin_amdgcn_rcpf(1.0f + __expf(-x));
}

__device__ __forceinline__ unsigned short f2bf(float x){
  unsigned int b = __float_as_uint(x);
  unsigned int r = ((b >> 16) & 1u) + 0x7fffu;
  return (unsigned short)((b + r) >> 16);
}

__device__ __forceinline__ unsigned int pk2(float a, float b){
  return (unsigned int)f2bf(a) | ((unsigned int)f2bf(b) << 16);
}

__device__ __forceinline__ float bf2f(unsigned short v){
  return __uint_as_float(((unsigned int)v) << 16);
}

__device__ __forceinline__ void unp4(uint2 u, float* x){
  x[0] = __uint_as_float(u.x << 16);
  x[1] = __uint_as_float(u.x & 0xffff0000u);
  x[2] = __uint_as_float(u.y << 16);
  x[3] = __uint_as_float(u.y & 0xffff0000u);
}

// Real-basis CG structural-nonzero mask (superset-safe selection rules):
// parity: number of sin-type (m<0) indices must be even;
// magnitude: |m3| in {|m1|+|m2|, ||m1|-|m2||}.
__device__ __host__ constexpr bool cg_nz(int l1,int l2,int l3,int i,int j,int k){
  int m1=i-l1, m2=j-l2, m3=k-l3;
  int a1=m1<0?-m1:m1, a2=m2<0?-m2:m2, a3=m3<0?-m3:m3;
  int neg=(m1<0?1:0)+(m2<0?1:0)+(m3<0?1:0);
  bool par=(neg&1)==0;
  bool mag=(a3==a1+a2)||(a3==a1-a2)||(a3==a2-a1);
  return par&&mag;
}
__device__ __host__ constexpr bool m_nz(int l1,int l2,int l3,int i,int k){
  for(int j=0;j<2*l2+1;++j) if(cg_nz(l1,l2,l3,i,j,k)) return true;
  return false;
}

__device__ const int d_PL1[11] = {0,1,2,0,1,1,2,0,1,2,2};
__device__ const int d_PL2[11] = {0,1,2,1,0,2,1,2,1,0,2};
__device__ const int d_PL3[11] = {0,0,0,1,1,1,1,2,2,2,2};

// ---------------------------------------------------------------------------
// CG math (1/PATH_NORM folded). All paths have even l1+l2+l3 -> real part.
// ---------------------------------------------------------------------------
__device__ double factd(int n){ double r=1.0; for(int i=2;i<=n;++i) r*=(double)i; return r; }

__device__ double su2_elem(int l1,int l2,int l3,int m1,int m2){
  int m3=m1+m2;
  if (m3 < -l3 || m3 > l3) return 0.0;
  double pref = sqrt((double)(2*l3+1)*factd(l3+l1-l2)*factd(l3-l1+l2)*factd(l1+l2-l3)/factd(l1+l2+l3+1));
  pref *= sqrt(factd(l3+m3)*factd(l3-m3)*factd(l1-m1)*factd(l1+m1)*factd(l2-m2)*factd(l2+m2));
  double s=0.0;
  for (int k=0;k<=l1+l2-l3;++k){
    int t1=l1+l2-l3-k, t2=l1-m1-k, t3=l2+m2-k, t4=l3-l2+m1+k, t5=l3-l1-m2+k;
    if (t1<0||t2<0||t3<0||t4<0||t5<0) continue;
    double d = factd(k)*factd(t1)*factd(t2)*factd(t3)*factd(t4)*factd(t5);
    s += ((k&1)? -1.0:1.0)/d;
  }
  return pref*s;
}

__device__ void q_elem(int l,int a,int i,double& re,double& im){
  re=0.0; im=0.0;
  const double is2 = 0.7071067811865476;
  int m = a - l;
  if (m==0){ if (i==l) re=1.0; return; }
  if (m>0){
    if (i==l+m)      re = (m&1)? -is2: is2;
    else if (i==l-m) re = is2;
  } else {
    int mm=-m;
    if (i==l-mm)      im = is2;
    else if (i==l+mm) im = (mm&1)? is2 : -is2;
  }
}

// ---------------------------------------------------------------------------
// init kernel: blocks 0..10 = CG table; blocks 11..70 = weight packing.
// ---------------------------------------------------------------------------
__global__ void init_kernel(const float* __restrict__ Wm1,
                            const float* __restrict__ Wm2,
                            float* __restrict__ cgout,
                            unsigned short* __restrict__ Wm1p,
                            unsigned short* __restrict__ Wm2p)
{
  if (blockIdx.x < 11){
    int p = blockIdx.x;
    int t = threadIdx.x;
    if (t >= 125) return;
    int a = t/25, b = (t/5)%5, c = t%5;
    int l1=d_PL1[p], l2=d_PL2[p], l3=d_PL3[p];
    int n1=2*l1+1, n2=2*l2+1, n3=2*l3+1;
    float outv = 0.0f;
    if (a<n1 && b<n2 && c<n3){
      double acc = 0.0;
      for (int i=0;i<n1;++i)
        for (int j=0;j<n2;++j){
          int m1=i-l1, m2=j-l2;
          int m3=m1+m2;
          if (m3 < -l3 || m3 > l3) continue;
          double cv = su2_elem(l1,l2,l3,m1,m2);
          if (cv==0.0) continue;
          int k = m3 + l3;
          double a1r,a1i,a2r,a2i,a3r,a3i;
          q_elem(l1,a,i,a1r,a1i);
          q_elem(l2,b,j,a2r,a2i);
          q_elem(l3,c,k,a3r,a3i);
          double re = (a1r*a2r - a1i*a2i)*a3r + (a1r*a2i + a1i*a2r)*a3i;
          acc += cv*re;
        }
      double invn = (l3==0)? 0.5773502691896258 : 0.5;
      outv = (float)(acc*invn);
    }
    cgout[p*125 + (a*5+b)*5 + c] = outv;
  } else {
    int t = (blockIdx.x - 11)*256 + threadIdx.x;
    if (t < 4096){
      int j = t & 7, lane = (t>>3)&63, ks = (t>>9)&1, ni = t>>10;
      int k = ks*32 + (lane>>4)*8 + j;
      int col = ni*16 + (lane&15);
      Wm1p[t] = f2bf(Wm1[k*64+col]);
    }
    int t2 = t - 4096;
    if (t2 >= 0 && t2 < 11264){
      int j = t2 & 7, lane = (t2>>3)&63, ks = (t2>>9)&1, ni = t2>>10;
      int k = ks*32 + (lane>>4)*8 + j;
      int col = ni*16 + (lane&15);
      Wm2p[t2] = f2bf(Wm2[k*176+col]);
    }
  }
}

// ---------------------------------------------------------------------------
// Node up-projection -> bf16, iu-major layout (scaled 0.25):
// row: [0:16]=m0 ch; [16:64]=m1 as [iu][16ch]; [64:144]=m2 as [iu][16ch]
// ---------------------------------------------------------------------------
__global__ __launch_bounds__(256) void node_up_kernel(
    const float* __restrict__ nf,
    const float* __restrict__ W0,
    const float* __restrict__ W1,
    const float* __restrict__ W2,
    unsigned short* __restrict__ mtabh)
{
  int gidx = blockIdx.x*256 + threadIdx.x;
  if (gidx >= NN*144) return;
  int n = gidx/144;
  int col = gidx - n*144;
  const float* f = nf + (size_t)n*144;
  float acc = 0.f;
  if (col < 16){
    int o = col;
    #pragma unroll
    for (int c=0;c<16;++c) acc += f[c]*W0[c*16+o];
  } else if (col < 64){
    int idx = col-16;
    int iu = idx >> 4, o = idx & 15;
    #pragma unroll
    for (int c=0;c<16;++c) acc += f[16+c*3+iu]*W1[c*16+o];
  } else {
    int idx = col-64;
    int iu = idx >> 4, o = idx & 15;
    #pragma unroll
    for (int c=0;c<16;++c) acc += f[64+c*5+iu]*W2[c*16+o];
  }
  mtabh[gidx] = f2bf(0.25f*acc);
}

// ---------------------------------------------------------------------------
// CSR build
// ---------------------------------------------------------------------------
__global__ __launch_bounds__(256) void hist_kernel(
    const int* __restrict__ recv, int* __restrict__ counts)
{
  int e = blockIdx.x*256 + threadIdx.x;
  if (e < NE) atomicAdd(&counts[recv[e]], 1);
}

__global__ __launch_bounds__(1024) void scan_kernel(
    const int* __restrict__ counts, int* __restrict__ offsets,
    int* __restrict__ nb, int NC)
{
  __shared__ int part[1024];
  int t = threadIdx.x;
  int local[32];
  int s = 0;
  #pragma unroll
  for (int i=0;i<32;++i){ local[i]=counts[t*32+i]; s+=local[i]; }
  part[t]=s;
  __syncthreads();
  for (int off=1; off<1024; off<<=1){
    int v = (t>=off)? part[t-off] : 0;
    __syncthreads();
    part[t] += v;
    __syncthreads();
  }
  int base = part[t] - s;
  int run = base;
  #pragma unroll
  for (int i=0;i<32;++i){ offsets[t*32+i]=run; run+=local[i]; }
  if (t==1023) offsets[NN]=run;

  for (int i=1; i<NC; ++i){
    long long Ti = (long long)NE*i/NC;
    if ((long long)base <= Ti && Ti < (long long)part[t]){
      int run2 = base;
      #pragma unroll
      for (int k=0;k<32;++k){
        int nxt = run2 + local[k];
        if (run2 <= Ti && Ti < nxt) nb[i] = t*32 + k + 1;
        run2 = nxt;
      }
    }
  }
  if (t==0) nb[0]=0;
  if (t==1023) nb[NC]=NN;
}

__global__ __launch_bounds__(256) void scatter_kernel(
    const int* __restrict__ recv, const int* __restrict__ offsets,
    int* __restrict__ cursor, int* __restrict__ edge_sorted)
{
  int e = blockIdx.x*256 + threadIdx.x;
  if (e < NE){
    int r = recv[e];
    int pos = atomicAdd(&cursor[r], 1);
    edge_sorted[offsets[r] + pos] = e;
  }
}

// ---------------------------------------------------------------------------
// Edge MLP + mix with MFMA. Emits mixb planes + per-slot side data
// (ylm bf16 y1/y2, sedge sender id).
// ---------------------------------------------------------------------------
__global__ __launch_bounds__(256) void edge_mix_kernel(
    const float* __restrict__ vectors,
    const int* __restrict__ senders,
    const int* __restrict__ edge_sorted,
    const int* __restrict__ offsets,
    const int* __restrict__ nb,
    const float* __restrict__ Wm0,
    const unsigned short* __restrict__ Wm1p,
    const unsigned short* __restrict__ Wm2p,
    int ci, int plane_stride,
    unsigned short* __restrict__ mixb,
    unsigned short* __restrict__ ylm,
    int* __restrict__ sedge)
{
  __shared__ unsigned short lds_h[4][8*64*8];
  __shared__ float lds_s[4][64];

  int sbase = offsets[nb[ci]];
  int nE = offsets[nb[ci+1]] - sbase;
  int tid = threadIdx.x;
  int wid = tid >> 6;
  int lane = tid & 63;
  int g = lane >> 4;
  int l15 = lane & 15;
  int wb = blockIdx.x*256 + wid*64;
  int slot = wb + lane;

  float vx=0.f, vy=0.f, vz=0.f;
  int snd = 0;
  if (slot < nE){
    int e = edge_sorted[sbase + slot];
    vx = vectors[(size_t)e*3+0];
    vy = vectors[(size_t)e*3+1];
    vz = vectors[(size_t)e*3+2];
    snd = senders[e];
  }
  float r = sqrtf(vx*vx + vy*vy + vz*vz);
  float safe = (r > 1e-9f) ? r : 1.0f;
  float inv_safe = 1.0f/safe;

  const float PIf = 3.14159265358979f;
  float xc = fminf(r*0.25f, 1.0f);
  float s1 = __sinf(PIf*xc);
  float c1 = __cosf(PIf*xc);
  float env = 0.5f*(c1 + 1.0f);
  float pref = 0.70710678118f * env * inv_safe;
  float rb[8];
  {
    float sk=s1, ck=c1;
    rb[0]=pref*sk;
    #pragma unroll
    for (int k=1;k<8;++k){
      float sn = sk*c1 + ck*s1;
      float cn = ck*c1 - sk*s1;
      sk=sn; ck=cn;
      rb[k]=pref*sk;
    }
  }

  if (slot < nE){
    float ux=vx*inv_safe, uy=vy*inv_safe, uz=vz*inv_safe;
    const float SQ3  = 1.73205080757f;
    const float SQ15 = 3.87298334621f;
    union { uint4 u; unsigned short s[8]; } yv;
    yv.s[0]=f2bf(SQ3*uy);  yv.s[1]=f2bf(SQ3*uz);  yv.s[2]=f2bf(SQ3*ux);
    yv.s[3]=f2bf(SQ15*ux*uy);
    yv.s[4]=f2bf(SQ15*uy*uz);
    yv.s[5]=f2bf(1.11803398875f*(3.f*uz*uz-1.f));
    yv.s[6]=f2bf(SQ15*ux*uz);
    yv.s[7]=f2bf(1.93649167310f*(ux*ux-uy*uy));
    *(uint4*)(ylm + (size_t)slot*8) = yv.u;
    sedge[slot] = snd;
  }

  float h[64];
  #pragma unroll
  for (int o=0;o<64;++o) h[o]=0.f;
  #pragma unroll
  for (int i=0;i<8;++i){
    float ri = rb[i];
    #pragma unroll
    for (int o=0;o<64;++o) h[o] += ri*Wm0[i*64+o];
  }

  unsigned short* Lh = lds_h[wid];
  #pragma unroll
  for (int c=0;c<8;++c){
    union { unsigned int u[4]; short8v v; } pk;
    #pragma unroll
    for (int w=0;w<4;++w){
      float a0 = siluf(h[c*8+2*w  ]*0.3535533906f);
      float a1 = siluf(h[c*8+2*w+1]*0.3535533906f);
      pk.u[w] = pk2(a0, a1);
    }
    *(short8v*)(Lh + ((size_t)(c*64 + lane))*8) = pk.v;
  }
  lds_s[wid][lane] = (r == 0.0f) ? 0.0f : 0.125f;

  __syncthreads();

  short8v a[8];
  #pragma unroll
  for (int mi=0;mi<4;++mi){
    #pragma unroll
    for (int ks=0;ks<2;++ks)
      a[mi*2+ks] = *(short8v*)(Lh + ((size_t)((ks*4+g)*64 + mi*16 + l15))*8);
  }
  #pragma unroll 1
  for (int ni=0;ni<4;++ni){
    short8v b0 = *(short8v*)(Wm1p + ((size_t)((ni*2+0)*64 + lane))*8);
    short8v b1 = *(short8v*)(Wm1p + ((size_t)((ni*2+1)*64 + lane))*8);
    int chnk = ni*2 + (l15>>3);
    int cb = l15 & 7;
    #pragma unroll
    for (int mi=0;mi<4;++mi){
      f32x4 acc = {0.f,0.f,0.f,0.f};
      acc = __builtin_amdgcn_mfma_f32_16x16x32_bf16(a[mi*2+0], b0, acc, 0,0,0);
      acc = __builtin_amdgcn_mfma_f32_16x16x32_bf16(a[mi*2+1], b1, acc, 0,0,0);
      #pragma unroll
      for (int reg=0;reg<4;++reg){
        int row = mi*16 + g*4 + reg;
        Lh[((size_t)(chnk*64 + row))*8 + cb] = f2bf(siluf(acc[reg]*0.125f));
      }
    }
  }

  short8v a2[8];
  #pragma unroll
  for (int mi=0;mi<4;++mi){
    #pragma unroll
    for (int ks=0;ks<2;++ks)
      a2[mi*2+ks] = *(short8v*)(Lh + ((size_t)((ks*4+g)*64 + mi*16 + l15))*8);
  }
  f32x4 scv[4];
  #pragma unroll
  for (int mi=0;mi<4;++mi)
    scv[mi] = *(f32x4*)(&lds_s[wid][mi*16 + g*4]);

  #pragma unroll 1
  for (int ni=0;ni<11;++ni){
    short8v b0 = *(short8v*)(Wm2p + ((size_t)((ni*2+0)*64 + lane))*8);
    short8v b1 = *(short8v*)(Wm2p + ((size_t)((ni*2+1)*64 + lane))*8);
    #pragma unroll
    for (int mi=0;mi<4;++mi){
      f32x4 acc = {0.f,0.f,0.f,0.f};
      acc = __builtin_amdgcn_mfma_f32_16x16x32_bf16(a2[mi*2+0], b0, acc, 0,0,0);
      acc = __builtin_amdgcn_mfma_f32_16x16x32_bf16(a2[mi*2+1], b1, acc, 0,0,0);
      #pragma unroll
      for (int reg=0;reg<4;++reg){
        int row = mi*16 + g*4 + reg;
        int sl = wb + row;
        if (sl < nE)
          mixb[((size_t)ni*plane_stride + sl)*16 + l15] = f2bf(acc[reg]*scv[mi][reg]);
      }
    }
  }
}

// ---------------------------------------------------------------------------
// Edge-parallel tensor product with compile-time CG sparsity pruning.
// Paths ordered by L3 group; msg written out per group.
// ---------------------------------------------------------------------------
template<int PIDX,int L1,int L2,int L3>
__device__ __forceinline__ void do_p(
    const float* __restrict__ cgtab, uint2 um,
    const float (&y1)[3], const float (&y2)[5],
    const float (&x0)[4], const float (&x1)[3][4], const float (&x2)[5][4],
    float (&msg0)[4], float (&msg1)[4][3], float (&msg2)[4][5])
{
  constexpr int d1=2*L1+1, d2=2*L2+1, d3=2*L3+1;
  const float* cgp = cgtab + PIDX*125;

  float yv[d2];
  if constexpr (L2==0){ yv[0]=1.0f; }
  else if constexpr (L2==1){ yv[0]=y1[0]; yv[1]=y1[1]; yv[2]=y1[2]; }
  else {
    #pragma unroll
    for (int j=0;j<5;++j) yv[j]=y2[j];
  }

  float M[d1][d3];
  #pragma unroll
  for (int iu=0;iu<d1;++iu){
    #pragma unroll
    for (int k=0;k<d3;++k){
      if (m_nz(L1,L2,L3,iu,k)){
        float acc = 0.f;
        #pragma unroll
        for (int j=0;j<d2;++j)
          if (cg_nz(L1,L2,L3,iu,j,k)) acc += yv[j]*cgp[(iu*5+j)*5+k];
        M[iu][k]=acc;
      } else {
        M[iu][k]=0.f;
      }
    }
  }

  float mx[4];
  mx[0] = __uint_as_float(um.x << 16);
  mx[1] = __uint_as_float(um.x & 0xffff0000u);
  mx[2] = __uint_as_float(um.y << 16);
  mx[3] = __uint_as_float(um.y & 0xffff0000u);

  #pragma unroll
  for (int c=0;c<4;++c){
    #pragma unroll
    for (int k=0;k<d3;++k){
      float t = 0.f;
      #pragma unroll
      for (int iu=0;iu<d1;++iu){
        if (m_nz(L1,L2,L3,iu,k)){
          float xv = (L1==0)? x0[c] : (L1==1? x1[iu][c] : x2[iu][c]);
          t += xv*M[iu][k];
        }
      }
      if constexpr (L3==0)      msg0[c]    += mx[c]*t;
      else if constexpr (L3==1) msg1[c][k] += mx[c]*t;
      else                      msg2[c][k] += mx[c]*t;
    }
  }
}

__global__ __launch_bounds__(256) void tp_kernel(
    const int* __restrict__ offsets,
    const int* __restrict__ nb,
    const unsigned short* __restrict__ mtabh,
    const float* __restrict__ cgtab,
    const unsigned short* __restrict__ mixb,
    const unsigned short* __restrict__ ylm,
    const int* __restrict__ sedge,
    int ci, int plane_stride,
    unsigned short* __restrict__ msgb)
{
  int t = blockIdx.x*256 + threadIdx.x;
  int slot = t >> 2;
  int sbase = offsets[nb[ci]];
  int nE = offsets[nb[ci+1]] - sbase;
  if (slot >= nE) return;
  int c0 = (t & 3)*4;

  union { uint4 u; unsigned short s[8]; } yv;
  yv.u = *(const uint4*)(ylm + (size_t)slot*8);
  int snd = sedge[slot];
  const unsigned short* xp = mtabh + (size_t)snd*144;

  float x0[4];
  float x1[3][4];
  float x2[5][4];
  unp4(*(const uint2*)(xp + c0), x0);
  #pragma unroll
  for (int iu=0;iu<3;++iu) unp4(*(const uint2*)(xp + 16 + iu*16 + c0), x1[iu]);
  #pragma unroll
  for (int iu=0;iu<5;++iu) unp4(*(const uint2*)(xp + 64 + iu*16 + c0), x2[iu]);

  float y1[3], y2[5];
  y1[0]=bf2f(yv.s[0]); y1[1]=bf2f(yv.s[1]); y1[2]=bf2f(yv.s[2]);
  y2[0]=bf2f(yv.s[3]); y2[1]=bf2f(yv.s[4]); y2[2]=bf2f(yv.s[5]);
  y2[3]=bf2f(yv.s[6]); y2[4]=bf2f(yv.s[7]);

  float msg0[4];
  float msg1[4][3];
  float msg2[4][5];
  #pragma unroll
  for (int c=0;c<4;++c){
    msg0[c]=0.f;
    #pragma unroll
    for (int i=0;i<3;++i) msg1[c][i]=0.f;
    #pragma unroll
    for (int i=0;i<5;++i) msg2[c][i]=0.f;
  }

  unsigned short* mr = msgb + (size_t)slot*144;
  #define UM(P) (*(const uint2*)(mixb + ((size_t)(P)*plane_stride + slot)*16 + c0))

  // ---- L3 = 0 group ----
  do_p< 0,0,0,0>(cgtab,UM(0),y1,y2,x0,x1,x2,msg0,msg1,msg2);
  do_p< 1,1,1,0>(cgtab,UM(1),y1,y2,x0,x1,x2,msg0,msg1,msg2);
  do_p< 2,2,2,0>(cgtab,UM(2),y1,y2,x0,x1,x2,msg0,msg1,msg2);
  {
    uint2 w;
    w.x = pk2(msg0[0], msg0[1]);
    w.y = pk2(msg0[2], msg0[3]);
    *(uint2*)(mr + c0) = w;
  }

  // ---- L3 = 1 group ----
  do_p< 3,0,1,1>(cgtab,UM(3),y1,y2,x0,x1,x2,msg0,msg1,msg2);
  do_p< 4,1,0,1>(cgtab,UM(4),y1,y2,x0,x1,x2,msg0,msg1,msg2);
  do_p< 5,1,2,1>(cgtab,UM(5),y1,y2,x0,x1,x2,msg0,msg1,msg2);
  do_p< 6,2,1,1>(cgtab,UM(6),y1,y2,x0,x1,x2,msg0,msg1,msg2);
  {
    unsigned short* p = mr + 16 + c0*3;
    uint2 w0, w1, w2;
    w0.x = pk2(msg1[0][0], msg1[0][1]);
    w0.y = pk2(msg1[0][2], msg1[1][0]);
    w1.x = pk2(msg1[1][1], msg1[1][2]);
    w1.y = pk2(msg1[2][0], msg1[2][1]);
    w2.x = pk2(msg1[2][2], msg1[3][0]);
    w2.y = pk2(msg1[3][1], msg1[3][2]);
    *(uint2*)(p) = w0;
    *(uint2*)(p+4) = w1;
    *(uint2*)(p+8) = w2;
  }

  // ---- L3 = 2 group ----
  do_p< 7,0,2,2>(cgtab,UM(7),y1,y2,x0,x1,x2,msg0,msg1,msg2);
  do_p< 8,1,1,2>(cgtab,UM(8),y1,y2,x0,x1,x2,msg0,msg1,msg2);
  do_p< 9,2,0,2>(cgtab,UM(9),y1,y2,x0,x1,x2,msg0,msg1,msg2);
  do_p<10,2,2,2>(cgtab,UM(10),y1,y2,x0,x1,x2,msg0,msg1,msg2);
  {
    unsigned short* p = mr + 64 + c0*5;
    #pragma unroll
    for (int w=0; w<5; ++w){
      int i0 = w*4;
      float v0 = msg2[(i0+0)/5][(i0+0)%5];
      float v1 = msg2[(i0+1)/5][(i0+1)%5];
      float v2 = msg2[(i0+2)/5][(i0+2)%5];
      float v3 = msg2[(i0+3)/5][(i0+3)%5];
      uint2 ww;
      ww.x = pk2(v0, v1);
      ww.y = pk2(v2, v3);
      *(uint2*)(p + i0) = ww;
    }
  }
  #undef UM
}

// ---------------------------------------------------------------------------
// Fused segmented-sum + node update. Block = 16 nodes x 16 threads.
// ---------------------------------------------------------------------------
__global__ __launch_bounds__(256) void seg_out_kernel(
    const int* __restrict__ offsets,
    const int* __restrict__ nb,
    const unsigned short* __restrict__ msgb,
    const float* __restrict__ nf,
    const int* __restrict__ species,
    const float* __restrict__ Wd0,
    const float* __restrict__ Wd1,
    const float* __restrict__ Wd2,
    const float* __restrict__ Wsk0,
    const float* __restrict__ Wsk1,
    const float* __restrict__ Wsk2,
    int ci,
    float* __restrict__ out)
{
  __shared__ float accum[16*144];

  int nlo = nb[ci], nhi = nb[ci+1];
  int nblk = blockIdx.x*16;
  if (nblk + 16 <= nlo || nblk >= nhi) return;

  int tid = threadIdx.x;
  int nloc = tid >> 4;
  int o = tid & 15;
  int n = nblk + nloc;
  bool active = (n >= nlo && n < nhi);

  int cbase = offsets[nlo];
  float acc[9];
  #pragma unroll
  for (int k=0;k<9;++k) acc[k]=0.f;
  if (active){
    int j0 = offsets[n] - cbase;
    int j1 = offsets[n+1] - cbase;
    for (int j=j0; j<j1; ++j){
      const unsigned short* mr = msgb + (size_t)j*144 + o*9;
      #pragma unroll
      for (int k=0;k<9;++k) acc[k] += bf2f(mr[k]);
    }
  }
  #pragma unroll
  for (int k=0;k<9;++k) accum[nloc*144 + o*9 + k] = acc[k];
  __syncthreads();
  if (!active) return;

  const float* an = accum + nloc*144;
  const float* f  = nf + (size_t)n*144;
  int sp = species[n];
  const float* wk0 = Wsk0 + sp*768;
  const float* wk1 = Wsk1 + sp*256;
  const float* wk2 = Wsk2 + sp*256;

  float sa0=0,sa1=0,sa2=0, sf0=0,sf1=0,sf2=0;
  #pragma unroll
  for (int c=0;c<16;++c){
    float aa = an[c], ff = f[c];
    sa0 += aa*Wd0[c*48+o];
    sa1 += aa*Wd0[c*48+16+o];
    sa2 += aa*Wd0[c*48+32+o];
    sf0 += ff*wk0[c*48+o];
    sf1 += ff*wk0[c*48+16+o];
    sf2 += ff*wk0[c*48+32+o];
  }
  float s0 = 0.0625f*sa0 + 0.25f*sf0;
  float s1 = 0.0625f*sa1 + 0.25f*sf1;
  float s2 = 0.0625f*sa2 + 0.25f*sf2;
  float scvv = siluf(s0);
  float g1  = siluf(s1);
  float g2  = siluf(s2);

  float v[3];
  #pragma unroll
  for (int i=0;i<3;++i){
    float av=0, fv=0;
    #pragma unroll
    for (int c=0;c<16;++c){
      av += an[16+c*3+i]*Wd1[c*16+o];
      fv += f[16+c*3+i]*wk1[c*16+o];
    }
    v[i] = (0.0625f*av + 0.25f*fv)*g1;
  }
  float q[5];
  #pragma unroll
  for (int i=0;i<5;++i){
    float av=0, fv=0;
    #pragma unroll
    for (int c=0;c<16;++c){
      av += an[64+c*5+i]*Wd2[c*16+o];
      fv += f[64+c*5+i]*wk2[c*16+o];
    }
    q[i] = (0.0625f*av + 0.25f*fv)*g2;
  }

  float* on = out + (size_t)n*144;
  on[o] = scvv;
  #pragma unroll
  for (int i=0;i<3;++i) on[16+o*3+i] = v[i];
  #pragma unroll
  for (int i=0;i<5;++i) on[64+o*5+i] = q[i];
}

// ---------------------------------------------------------------------------
extern "C" void kernel_launch(void* const* d_in, const int* in_sizes, int n_in,
                              void* d_out, int out_size, void* d_ws, size_t ws_size,
                              hipStream_t stream)
{
  const float* vectors    = (const float*)d_in[0];
  const float* node_feats = (const float*)d_in[1];
  const int*   species    = (const int*)d_in[2];
  const int*   senders    = (const int*)d_in[3];
  const int*   receivers  = (const int*)d_in[4];
  const float* W_up0 = (const float*)d_in[5];
  const float* W_up1 = (const float*)d_in[6];
  const float* W_up2 = (const float*)d_in[7];
  const float* Wm0   = (const float*)d_in[8];
  const float* Wm1   = (const float*)d_in[9];
  const float* Wm2   = (const float*)d_in[10];
  const float* Wd0   = (const float*)d_in[11];
  const float* Wd1   = (const float*)d_in[12];
  const float* Wd2   = (const float*)d_in[13];
  const float* Wsk0  = (const float*)d_in[14];
  const float* Wsk1  = (const float*)d_in[15];
  const float* Wsk2  = (const float*)d_in[16];
  float* out = (float*)d_out;
  float* ws  = (float*)d_ws;

  float* cgbuf = ws;
  unsigned short* mtabh = (unsigned short*)(ws + 2048);
  int* counts      = (int*)(ws + 2048 + (size_t)NN*72);
  int* cursor      = counts + NN;
  int* offsets     = cursor + NN;
  int* edge_sorted = offsets + NN + 64;
  int* nb          = edge_sorted + NE;
  unsigned short* Wm1p = (unsigned short*)(nb + 16);
  unsigned short* Wm2p = Wm1p + 4096;
  unsigned short* mixb = Wm2p + 11264;

  size_t fixed_f = 2048 + (size_t)NN*72 + NN + NN + (NN+64) + NE + 16 + 2048 + 5632;
  size_t ws_f = ws_size/4;
  // per-edge ws: mixb 88f + ylm 4f + sedge 1f + msgb 72f = 165 f
  long long cap_rows = (ws_f > fixed_f) ? (long long)((ws_f - fixed_f)/165) : 0;
  long long capm = cap_rows - 8192;
  if (capm < 16384) capm = 16384;
  int NC = (int)((NE + capm - 1)/capm);
  if (NC < 1) NC = 1;
  if (NC > 15) NC = 15;
  int plane_stride = (int)(NE/NC + 4096);

  unsigned short* ylm  = mixb + (size_t)11*plane_stride*16;
  int* sedge           = (int*)(ylm + (size_t)plane_stride*8);
  unsigned short* msgb = (unsigned short*)(sedge + plane_stride);

  hipMemsetAsync(counts, 0, 2*(size_t)NN*sizeof(int), stream);
  init_kernel<<<71, 256, 0, stream>>>(Wm1, Wm2, cgbuf, Wm1p, Wm2p);
  node_up_kernel<<<(NN*144)/256, 256, 0, stream>>>(node_feats, W_up0, W_up1, W_up2, mtabh);
  hist_kernel<<<NE/256, 256, 0, stream>>>(receivers, counts);
  scan_kernel<<<1, 1024, 0, stream>>>(counts, offsets, nb, NC);
  scatter_kernel<<<NE/256, 256, 0, stream>>>(receivers, offsets, cursor, edge_sorted);

  long long chunk_edges_max = NE/NC + 4096;
  int gA  = (int)((chunk_edges_max + 255)/256);
  int gTP = (int)((chunk_edges_max*4 + 255)/256);
  int gSO = (NN + 15)/16;
  for (int ci = 0; ci < NC; ++ci){
    edge_mix_kernel<<<gA, 256, 0, stream>>>(vectors, senders, edge_sorted,
                                            offsets, nb, Wm0, Wm1p, Wm2p,
                                            ci, plane_stride, mixb, ylm, sedge);
    tp_kernel<<<gTP, 256, 0, stream>>>(offsets, nb, mtabh, cgbuf, mixb, ylm,
                                       sedge, ci, plane_stride, msgb);
    seg_out_kernel<<<gSO, 256, 0, stream>>>(offsets, nb, msgb, node_feats,
                                            species, Wd0, Wd1, Wd2,
                                            Wsk0, Wsk1, Wsk2, ci, out);
  }
}